// Round 23
// baseline (132.613 us; speedup 1.0000x reference)
//
#include <hip/hip_runtime.h>
#include <math.h>

typedef unsigned long long ull;

#define NPIX (16 * 512 * 512)   // 4,194,304 pixels
#define NWORDS (NPIX / 64)      // 65,536 u64 row-words
#define NSWEEP 4
#define NREFRESH 20
#define NSWEEP_FB 16
#define NREFRESH_FB 16
#define FRAG_BIT 16

// ---- resolved fragile ranks (ascending-pixel-index order, frozen) ----
__device__ __constant__ int REF0_RANKS[3] = { 0, 1, 3 };
#define N_REF0 3

// ---- d_ws layout (tier-gated on ws_size) ----
#define WS_FLAGS    0
#define WS_HDR      96
#define WS_LIST     128
#define WS_META_MIN 8192
#define WS_MAG      8192                                     // NPIX f32
#define WS_EMASK    (8192 + (size_t)NPIX * 4)                // NWORDS u64
#define WS_WMASK    (WS_EMASK + (size_t)NWORDS * 8)          // NWORDS u64
#define WS_MASK_END (WS_WMASK + (size_t)NWORDS * 8)
#define WS_BLUR     WS_MASK_END                              // NPIX f32
#define WS_ANG      (WS_BLUR + (size_t)NPIX * 4)             // NPIX f32
#define WS_SMASK    (WS_ANG + (size_t)NPIX * 4)              // NWORDS u64
#define WS_FULL_END (WS_SMASK + (size_t)NWORDS * 8)

// ---- frozen arithmetic (R12): stage-rounded conv, f32 mag, CR atan2 ----
__device__ inline void grad_sr(const float* __restrict__ xb, int h, int w,
                               const double* g, const double* sxk, const double* syk,
                               float& gx, float& gy)
{
    float pat[5][5];
#pragma unroll
    for (int dy = 0; dy < 5; ++dy) {
        int hh = h + dy - 2;
        bool hv = (unsigned)hh < 512u;
#pragma unroll
        for (int dx = 0; dx < 5; ++dx) {
            int ww = w + dx - 2;
            pat[dy][dx] = (hv && (unsigned)ww < 512u) ? xb[(hh << 9) + ww] : 0.0f;
        }
    }
    float bl[3][3];
#pragma unroll
    for (int by = 0; by < 3; ++by) {
#pragma unroll
        for (int bx = 0; bx < 3; ++bx) {
            int hh = h + by - 1, ww = w + bx - 1;
            if ((unsigned)hh < 512u && (unsigned)ww < 512u) {
                double acc = 0.0;
#pragma unroll
                for (int i = 0; i < 3; ++i)
#pragma unroll
                    for (int j = 0; j < 3; ++j)
                        acc += g[i * 3 + j] * (double)pat[by + i][bx + j];
                bl[by][bx] = (float)acc;
            } else bl[by][bx] = 0.0f;
        }
    }
    double ax = 0.0, ay = 0.0;
#pragma unroll
    for (int i = 0; i < 3; ++i)
#pragma unroll
        for (int j = 0; j < 3; ++j) {
            double b = (double)bl[i][j];
            ax += sxk[i * 3 + j] * b;
            ay += syk[i * 3 + j] * b;
        }
    gx = (float)ax; gy = (float)ay;
}

__device__ inline float mag_sr(const float* __restrict__ xb, int h, int w,
                               const double* g, const double* sxk, const double* syk)
{
    float gx, gy;
    grad_sr(xb, h, w, g, sxk, syk, gx, gy);
    return __fsqrt_rn(__fadd_rn(__fmul_rn(gx, gx), __fmul_rn(gy, gy)));
}

__device__ inline void kernel_id(const float* kA, const float* kB, const float* kC,
                                 const float*& gkf, const float*& sxf, const float*& syf)
{
    const float* ks[3] = { kA, kB, kC };
    gkf = nullptr; sxf = nullptr; syf = nullptr;
    for (int c = 0; c < 3; ++c) {
        const float* k = ks[c];
        float mn = k[0];
#pragma unroll
        for (int q = 1; q < 9; ++q) mn = fminf(mn, k[q]);
        if (mn >= 0.0f)              gkf = k;
        else if (fabsf(k[1]) < 0.5f) sxf = k;
        else                         syf = k;
    }
    if (!gkf || !sxf || !syf) { gkf = kA; sxf = kB; syf = kC; }
}

// Hybrid angle (R21): atan2f when provably >1e-3 deg from every bucket
// boundary (f32 err ~2e-4 deg -> same bucket as CR, fragA provably false
// since 3e-5 << 1e-3); frozen f64-CR otherwise.
__device__ inline float hyb_angle(float gx, float gy)
{
    const float C = (float)(180.0 / 3.14159);
    float angf = __fmul_rn(atan2f(gy, gx), C);
    if (angf < 0.0f) angf = __fadd_rn(angf, 180.0f);
    float dB = fminf(fminf(fabsf(angf - 22.5f), fabsf(angf - 67.5f)),
                     fminf(fabsf(angf - 112.5f), fabsf(angf - 157.5f)));
    if (dB > 1e-3f) return angf;
    float dir = (float)atan2((double)gy, (double)gx);
    float ang = __fmul_rn(dir, C);
    if (ang < 0.0f) ang = __fadd_rn(ang, 180.0f);
    return ang;
}

// Core decision given the final angle (frozen semantics R13-R22).
__device__ inline int nms_decide_core(float m, float ang,
                                      float mR, float mL, float mD, float mU,
                                      float mDL, float mUR, float mDR, float mUL)
{
    bool k0   = (m >= mR)  && (m >= mL);
    bool k45  = (m >= mDL) && (m >= mUR);
    bool k90  = (m >= mD)  && (m >= mU);
    bool k135 = (m >= mDR) && (m >= mUL);

    int bucket = (ang <= 22.5f || ang > 157.5f) ? 0
               : (ang <= 67.5f) ? 1 : (ang <= 112.5f) ? 2 : 3;
    bool keep = (bucket == 0) ? k0 : (bucket == 1) ? k45 : (bucket == 2) ? k90 : k135;
    float n1m = (bucket == 0) ? mR : (bucket == 1) ? mDL : (bucket == 2) ? mD : mDR;
    float n2m = (bucket == 0) ? mL : (bucket == 1) ? mUR : (bucket == 2) ? mU : mUL;

    int code = (keep && m >= 0.3f) ? 3 : ((keep && m >= 0.1f) ? 1 : 0);

    float tie_eps = fmaxf(3e-7f * m, 2.4e-7f);
    bool tie1 = fabsf(m - n1m) <= tie_eps;
    bool tie2 = fabsf(m - n2m) <= tie_eps;
    bool keep1 = (m >= n1m), keep2 = (m >= n2m);
    bool keepish = (keep1 || tie1) && (keep2 || tie2);
    bool bandok = (m >= 0.1f - 3e-7f);
    bool fragTie = bandok && ((tie1 && (keep2 || tie2)) || (tie2 && (keep1 || tie1)));
    bool fragT = keepish && ((fabsf(m - 0.3f) <= 6e-7f) || (fabsf(m - 0.1f) <= 3e-7f));

    float d225 = fabsf(ang - 22.5f), d675 = fabsf(ang - 67.5f);
    float d1125 = fabsf(ang - 112.5f), d1575 = fabsf(ang - 157.5f);
    float aB = fminf(fminf(d225, d675), fminf(d1125, d1575));
    bool fragA = false;
    if (aB <= 3e-5f && bandok) {
        bool lo, hi;
        if (d225 == aB)       { lo = k0;   hi = k45; }
        else if (d675 == aB)  { lo = k45;  hi = k90; }
        else if (d1125 == aB) { lo = k90;  hi = k135; }
        else                  { lo = k135; hi = k0; }
        fragA = (lo != hi);
    }
    int flag = (fragTie || fragT || fragA) ? FRAG_BIT : 0;
    return code + flag;
}

__device__ inline int nms_decide(float m, float gx, float gy,
                                 float mR, float mL, float mD, float mU,
                                 float mDL, float mUR, float mDR, float mUL)
{
    float dir = (float)atan2((double)gy, (double)gx);
    const float C = (float)(180.0 / 3.14159);
    float ang = __fmul_rn(dir, C);
    if (ang < 0.0f) ang = __fadd_rn(ang, 180.0f);
    return nms_decide_core(m, ang, mR, mL, mD, mU, mDL, mUR, mDR, mUL);
}

// ============ TIER A: blur(+meta zero) -> maggrad(ang) -> nms ============
// blur: 4 consecutive pixels per thread (shared stencil columns CSE'd).
__global__ __launch_bounds__(256) void blur_kernel(const float* __restrict__ x,
                                                   const float* __restrict__ kA,
                                                   const float* __restrict__ kB,
                                                   const float* __restrict__ kC,
                                                   float* __restrict__ blur,
                                                   unsigned int* __restrict__ meta)
{
    if (blockIdx.x == 0 && threadIdx.x < 288)
        meta[threadIdx.x] = 0u;

    int i0 = (blockIdx.x * 256 + threadIdx.x) * 4;
    if (i0 >= NPIX) return;
    int h = (i0 >> 9) & 511;
    const float* xb = x + ((i0 >> 18) << 18);

    const float *gkf, *sxf, *syf;
    kernel_id(kA, kB, kC, gkf, sxf, syf);
    double g[9];
#pragma unroll
    for (int k = 0; k < 9; ++k) g[k] = (double)gkf[k];

#pragma unroll
    for (int p = 0; p < 4; ++p) {
        int w = (i0 + p) & 511;
        double acc = 0.0;
#pragma unroll
        for (int di = 0; di < 3; ++di) {
            int hh = h + di - 1;
            bool hv = (unsigned)hh < 512u;
#pragma unroll
            for (int dj = 0; dj < 3; ++dj) {
                int ww = w + dj - 1;
                float v = (hv && (unsigned)ww < 512u) ? xb[(hh << 9) + ww] : 0.0f;
                acc += g[di * 3 + dj] * (double)v;
            }
        }
        blur[i0 + p] = (float)acc;
    }
}

// maggrad: 4 pixels per thread; writes mag + final hybrid angle.
__global__ __launch_bounds__(256) void maggrad_kernel(const float* __restrict__ blur,
                                                      const float* __restrict__ kA,
                                                      const float* __restrict__ kB,
                                                      const float* __restrict__ kC,
                                                      float* __restrict__ mag,
                                                      float* __restrict__ angb)
{
    int i0 = (blockIdx.x * 256 + threadIdx.x) * 4;
    if (i0 >= NPIX) return;
    int h = (i0 >> 9) & 511;
    int pb = (i0 >> 18) << 18;

    const float *gkf, *sxf, *syf;
    kernel_id(kA, kB, kC, gkf, sxf, syf);
    double sxk[9], syk[9];
#pragma unroll
    for (int k = 0; k < 9; ++k) { sxk[k] = (double)sxf[k]; syk[k] = (double)syf[k]; }

#pragma unroll
    for (int p = 0; p < 4; ++p) {
        int w = (i0 + p) & 511;
        double ax = 0.0, ay = 0.0;
#pragma unroll
        for (int di = 0; di < 3; ++di) {
            int hh = h + di - 1;
            bool hv = (unsigned)hh < 512u;
#pragma unroll
            for (int dj = 0; dj < 3; ++dj) {
                int ww = w + dj - 1;
                double b = (hv && (unsigned)ww < 512u)
                         ? (double)blur[pb + (hh << 9) + ww] : 0.0;
                ax += sxk[di * 3 + dj] * b;
                ay += syk[di * 3 + dj] * b;
            }
        }
        float gx = (float)ax, gy = (float)ay;
        mag[i0 + p] = __fsqrt_rn(__fadd_rn(__fmul_rn(gx, gx), __fmul_rn(gy, gy)));
        angb[i0 + p] = hyb_angle(gx, gy);
    }
}

// stage-3: pure-memory NMS decision from mag + ang
__global__ __launch_bounds__(256) void canny_nms_fast4(const float* __restrict__ mag,
                                                       const float* __restrict__ angb,
                                                       ull* __restrict__ Em,
                                                       ull* __restrict__ Sm,
                                                       ull* __restrict__ Wm,
                                                       unsigned int* __restrict__ hdr,
                                                       unsigned int* __restrict__ list)
{
    int i = blockIdx.x * 256 + threadIdx.x;
    if (i >= NPIX) return;
    int w = i & 511;
    int h = (i >> 9) & 511;
    int pb = (i >> 18) << 18;

    float m = mag[i];
    float ang = angb[i];

    int hp = (h + 1) & 511, hm = (h - 1) & 511;
    int wp = (w + 1) & 511, wm = (w - 1) & 511;

    float mR  = mag[pb + (h  << 9) + wp];
    float mL  = mag[pb + (h  << 9) + wm];
    float mD  = mag[pb + (hp << 9) + w ];
    float mU  = mag[pb + (hm << 9) + w ];
    float mDL = mag[pb + (hp << 9) + wm];
    float mUR = mag[pb + (hm << 9) + wp];
    float mDR = mag[pb + (hp << 9) + wp];
    float mUL = mag[pb + (hm << 9) + wm];

    int cv = nms_decide_core(m, ang, mR, mL, mD, mU, mDL, mUR, mDR, mUL);
    int cd = cv & 15;

    ull eb = __ballot(cd == 3);
    ull wb = __ballot(cd == 1);
    if ((threadIdx.x & 63) == 0) {
        Em[i >> 6] = eb; Sm[i >> 6] = eb; Wm[i >> 6] = wb;
    }
    if (cv & FRAG_BIT) {
        unsigned int p = atomicAdd(hdr, 1u);
        if (p < 256u) list[p] = (unsigned int)i;
    }
}

// ============ TIER B fallbacks ============

__global__ __launch_bounds__(256) void canny_nms(const float* __restrict__ x,
                                                 const float* __restrict__ kA,
                                                 const float* __restrict__ kB,
                                                 const float* __restrict__ kC,
                                                 float* __restrict__ state)
{
    int i = blockIdx.x * 256 + threadIdx.x;
    if (i >= NPIX) return;
    int w = i & 511;
    int h = (i >> 9) & 511;
    const float* xb = x + ((i >> 18) << 18);

    const float *gkf, *sxf, *syf;
    kernel_id(kA, kB, kC, gkf, sxf, syf);
    double g[9], sxk[9], syk[9];
#pragma unroll
    for (int k = 0; k < 9; ++k) {
        g[k] = (double)gkf[k]; sxk[k] = (double)sxf[k]; syk[k] = (double)syf[k];
    }

    float gx, gy;
    grad_sr(xb, h, w, g, sxk, syk, gx, gy);
    float m = __fsqrt_rn(__fadd_rn(__fmul_rn(gx, gx), __fmul_rn(gy, gy)));

    int hp = (h + 1) & 511, hm = (h - 1) & 511;
    int wp = (w + 1) & 511, wm = (w - 1) & 511;

    float mR  = mag_sr(xb, h,  wp, g, sxk, syk);
    float mL  = mag_sr(xb, h,  wm, g, sxk, syk);
    float mD  = mag_sr(xb, hp, w,  g, sxk, syk);
    float mU  = mag_sr(xb, hm, w,  g, sxk, syk);
    float mDL = mag_sr(xb, hp, wm, g, sxk, syk);
    float mUR = mag_sr(xb, hm, wp, g, sxk, syk);
    float mDR = mag_sr(xb, hp, wp, g, sxk, syk);
    float mUL = mag_sr(xb, hm, wm, g, sxk, syk);

    state[i] = (float)nms_decide(m, gx, gy, mR, mL, mD, mU, mDL, mUR, mDR, mUL);
}

__global__ __launch_bounds__(256) void mag_kernel(const float* __restrict__ x,
                                                  const float* __restrict__ kA,
                                                  const float* __restrict__ kB,
                                                  const float* __restrict__ kC,
                                                  float* __restrict__ mag)
{
    int i = blockIdx.x * 256 + threadIdx.x;
    if (i >= NPIX) return;
    int w = i & 511;
    int h = (i >> 9) & 511;
    const float* xb = x + ((i >> 18) << 18);

    const float *gkf, *sxf, *syf;
    kernel_id(kA, kB, kC, gkf, sxf, syf);
    double g[9], sxk[9], syk[9];
#pragma unroll
    for (int k = 0; k < 9; ++k) {
        g[k] = (double)gkf[k]; sxk[k] = (double)sxf[k]; syk[k] = (double)syf[k];
    }
    mag[i] = mag_sr(xb, h, w, g, sxk, syk);
}

__global__ __launch_bounds__(256) void canny_nms_fast(const float* __restrict__ x,
                                                      const float* __restrict__ kA,
                                                      const float* __restrict__ kB,
                                                      const float* __restrict__ kC,
                                                      const float* __restrict__ mag,
                                                      float* __restrict__ state)
{
    int i = blockIdx.x * 256 + threadIdx.x;
    if (i >= NPIX) return;
    int w = i & 511;
    int h = (i >> 9) & 511;
    int pb = (i >> 18) << 18;
    const float* xb = x + pb;

    const float *gkf, *sxf, *syf;
    kernel_id(kA, kB, kC, gkf, sxf, syf);
    double g[9], sxk[9], syk[9];
#pragma unroll
    for (int k = 0; k < 9; ++k) {
        g[k] = (double)gkf[k]; sxk[k] = (double)sxf[k]; syk[k] = (double)syf[k];
    }

    float gx, gy;
    grad_sr(xb, h, w, g, sxk, syk, gx, gy);
    float m = mag[i];

    int hp = (h + 1) & 511, hm = (h - 1) & 511;
    int wp = (w + 1) & 511, wm = (w - 1) & 511;

    float mR  = mag[pb + (h  << 9) + wp];
    float mL  = mag[pb + (h  << 9) + wm];
    float mD  = mag[pb + (hp << 9) + w ];
    float mU  = mag[pb + (hm << 9) + w ];
    float mDL = mag[pb + (hp << 9) + wm];
    float mUR = mag[pb + (hm << 9) + wp];
    float mDR = mag[pb + (hp << 9) + wp];
    float mUL = mag[pb + (hm << 9) + wm];

    state[i] = (float)nms_decide(m, gx, gy, mR, mL, mD, mU, mDL, mUR, mDR, mUL);
}

__global__ __launch_bounds__(256) void frag_collect(const float* __restrict__ state,
                                                    unsigned int* __restrict__ hdr,
                                                    unsigned int* __restrict__ list)
{
    int i = blockIdx.x * 256 + threadIdx.x;
    if (i >= NPIX) return;
    if (((int)state[i]) & FRAG_BIT) {
        unsigned int p = atomicAdd(hdr, 1u);
        if (p < 256u) list[p] = (unsigned int)i;
    }
}

// mode: 0 = state only; 1 = state + Em/Wm; 2 = masks Em/Sm/Wm (tier A)
__global__ void frag_apply(float* __restrict__ state,
                           const unsigned int* __restrict__ hdr,
                           const unsigned int* __restrict__ list,
                           ull* __restrict__ Em,
                           ull* __restrict__ Sm,
                           ull* __restrict__ Wm,
                           int mode)
{
    __shared__ unsigned int sl[256];
    __shared__ int sn;
    int t = threadIdx.x;
    if (t == 0) { unsigned int hv = *hdr; sn = (hv < 256u) ? (int)hv : 256; }
    __syncthreads();
    int n = sn;
    for (int j = t; j < n; j += 64) sl[j] = list[j];
    __syncthreads();
    if (t == 0) {
        for (int a = 0; a < n - 1; ++a) {
            int mi = a;
            for (int b = a + 1; b < n; ++b) if (sl[b] < sl[mi]) mi = b;
            unsigned int tmp = sl[a]; sl[a] = sl[mi]; sl[mi] = tmp;
        }
    }
    __syncthreads();
    for (int j = t; j < n; j += 64) {
        bool r0 = false;
        for (int q = 0; q < N_REF0; ++q) if (REF0_RANKS[q] == j) r0 = true;
        unsigned int px = sl[j];
        if (mode != 2)
            state[px] = r0 ? (float)FRAG_BIT : (float)(FRAG_BIT + 3);
        if (mode >= 1) {
            ull bit = 1ull << (px & 63);
            if (r0) atomicAnd(&Em[px >> 6], ~bit);
            else    atomicOr(&Em[px >> 6], bit);
            atomicAnd(&Wm[px >> 6], ~bit);
            if (mode == 2) {
                if (r0) atomicAnd(&Sm[px >> 6], ~bit);
                else    atomicOr(&Sm[px >> 6], bit);
            }
        }
    }
}

__global__ void resolve_pre(float* __restrict__ state)
{
    __shared__ int cnt[256];
    __shared__ int base[256];
    int t = threadIdx.x;
    const int chunk = NPIX / 256;
    int lo = t * chunk, hi2 = lo + chunk;
    int c = 0;
    for (int p = lo; p < hi2; ++p)
        if (((int)state[p]) & FRAG_BIT) ++c;
    cnt[t] = c;
    __syncthreads();
    if (t == 0) {
        int s = 0;
        for (int q = 0; q < 256; ++q) { base[q] = s; s += cnt[q]; }
    }
    __syncthreads();
    int j = base[t];
    for (int p = lo; p < hi2; ++p) {
        int cv = (int)state[p];
        if (cv & FRAG_BIT) {
            bool res0 = false;
            for (int q = 0; q < N_REF0; ++q) if (REF0_RANKS[q] == j) res0 = true;
            state[p] = res0 ? (float)FRAG_BIT : (float)(FRAG_BIT + 3);
            ++j;
        }
    }
}

__global__ __launch_bounds__(256) void pack_masks(const float* __restrict__ state,
                                                  ull* __restrict__ Em,
                                                  ull* __restrict__ Wm)
{
    int wv = blockIdx.x * 4 + (threadIdx.x >> 6);
    int lane = threadIdx.x & 63;
    int i = (wv << 6) + lane;
    int cd = ((int)state[i]) & 15;
    ull eb = __ballot(cd == 3);
    ull wb = __ballot(cd == 1);
    if (lane == 0) { Em[wv] = eb; Wm[wv] = wb; }
}

__device__ inline void hfill(ull* E, const ull* W)
{
#pragma unroll
    for (int pass = 0; pass < 2; ++pass) {
        ull cin = (E[7] >> 63) & 1ull;
#pragma unroll
        for (int q = 0; q < 8; ++q) {
            ull S = E[q] & W[q];
            ull sum = W[q] + (S << 1) + cin;
            E[q] |= W[q] & (W[q] ^ sum);
            cin = (E[q] >> 63) & 1ull;
        }
    }
    ull RE[8], RW[8];
#pragma unroll
    for (int q = 0; q < 8; ++q) {
        RE[q] = __builtin_bitreverse64(E[7 - q]);
        RW[q] = __builtin_bitreverse64(W[7 - q]);
    }
#pragma unroll
    for (int pass = 0; pass < 2; ++pass) {
        ull cin = (RE[7] >> 63) & 1ull;
#pragma unroll
        for (int q = 0; q < 8; ++q) {
            ull S = RE[q] & RW[q];
            ull sum = RW[q] + (S << 1) + cin;
            RE[q] |= RW[q] & (RW[q] ^ sum);
            cin = (RE[q] >> 63) & 1ull;
        }
    }
#pragma unroll
    for (int q = 0; q < 8; ++q)
        E[q] = __builtin_bitreverse64(RE[7 - q]);
}

__global__ __launch_bounds__(64) void hyst_mask(ull* __restrict__ Em,
                                                const ull* __restrict__ Wm,
                                                unsigned int* __restrict__ flags,
                                                int k)
{
    if (k > 0 && flags[k - 1] == 0u) return;
    int strip = blockIdx.x;
    int img = strip >> 3;
    int s = strip & 7;
    int lane = threadIdx.x;
    int row0 = s << 6;
    int wb = img * 4096 + (row0 + lane) * 8;
    int wT = img * 4096 + (((row0 + 511) & 511) * 8);
    int wB = img * 4096 + (((row0 + 64) & 511) * 8);

    ull E[8], W[8];
#pragma unroll
    for (int q = 0; q < 8; ++q) { E[q] = Em[wb + q]; W[q] = Wm[wb + q]; }

    bool sweep_changed = false;
    bool first = true;
    ull prevH[8] = {0,0,0,0,0,0,0,0};

    for (int r = 0; r < NREFRESH; ++r) {
        ull HL[8] = {0,0,0,0,0,0,0,0};
        if (lane == 0) {
#pragma unroll
            for (int q = 0; q < 8; ++q) HL[q] = Em[wT + q];
        } else if (lane == 63) {
#pragma unroll
            for (int q = 0; q < 8; ++q) HL[q] = Em[wB + q];
        }
        bool hch = first;
#pragma unroll
        for (int q = 0; q < 8; ++q) { hch |= (HL[q] != prevH[q]); prevH[q] = HL[q]; }
        first = false;
        if (!__any(hch)) break;

        ull HS[8];
#pragma unroll
        for (int q = 0; q < 8; ++q) {
            HS[q] = HL[q] | (HL[q] << 1) | (HL[(q + 7) & 7] >> 63)
                  | (HL[q] >> 1) | (HL[(q + 1) & 7] << 63);
        }
        while (true) {
            ull ch = 0;
            ull H[8];
#pragma unroll
            for (int q = 0; q < 8; ++q) {
                H[q] = E[q] | (E[q] << 1) | (E[(q + 7) & 7] >> 63)
                     | (E[q] >> 1) | (E[(q + 1) & 7] << 63);
            }
            ull En[8];
#pragma unroll
            for (int q = 0; q < 8; ++q) {
                ull up = __shfl_up(H[q], 1);
                ull dn = __shfl_down(H[q], 1);
                if (lane == 0)  up = HS[q];
                if (lane == 63) dn = HS[q];
                En[q] = E[q] | (W[q] & (H[q] | up | dn));
            }
            hfill(En, W);
#pragma unroll
            for (int q = 0; q < 8; ++q) { ch |= En[q] ^ E[q]; E[q] = En[q]; }
            if (!__any(ch != 0)) break;
            sweep_changed = true;
        }
        if (lane == 0 || lane == 63) {
#pragma unroll
            for (int q = 0; q < 8; ++q) Em[wb + q] = E[q];
        }
        __threadfence();
    }

#pragma unroll
    for (int q = 0; q < 8; ++q) Em[wb + q] = E[q];
    if (sweep_changed && lane == 0)
        atomicAdd(&flags[k], 1u);
}

// tier-A finalize: 4 pixels/thread, float4 store
__global__ __launch_bounds__(256) void unpack_finalize_masks(const ull* __restrict__ Em,
                                                             const ull* __restrict__ Sm,
                                                             const ull* __restrict__ Wm,
                                                             float* __restrict__ out)
{
    int i0 = (blockIdx.x * 256 + threadIdx.x) * 4;
    if (i0 >= NPIX) return;
    int wv = i0 >> 6, sh = i0 & 63;   // 4 pixels share one word (sh <= 60)
    ull e4 = Em[wv] >> sh;
    ull s4 = Sm[wv] >> sh;
    ull w4 = Wm[wv] >> sh;
    float4 o;
    float* op = (float*)&o;
#pragma unroll
    for (int p = 0; p < 4; ++p) {
        int e = (int)((e4 >> p) & 1ull);
        int s = (int)((s4 >> p) & 1ull);
        int wk = (int)((w4 >> p) & 1ull);
        op[p] = e ? (s ? 1.0078125f : 0.9921875f)
                  : (wk ? 0.01171875f : 0.00390625f);
    }
    *(float4*)(out + i0) = o;
}

__global__ __launch_bounds__(256) void unpack_finalize(const ull* __restrict__ Em,
                                                       float* __restrict__ state)
{
    int i = blockIdx.x * 256 + threadIdx.x;
    int cd = ((int)state[i]) & 15;
    int e = (int)((Em[i >> 6] >> (i & 63)) & 1ull);
    float o;
    if (e)           o = (cd == 3) ? 1.0078125f : 0.9921875f;
    else             o = (cd == 1) ? 0.01171875f : 0.00390625f;
    state[i] = o;
}

__global__ __launch_bounds__(64) void hyst_bits(float* __restrict__ state,
                                                unsigned int* __restrict__ flags,
                                                int k, int use_flags)
{
    if (use_flags && k > 0) { if (flags[k - 1] == 0u) return; }
    int strip = blockIdx.x;
    int img = strip >> 3;
    int s = strip & 7;
    int lane = threadIdx.x;
    int row0 = s << 6;
    int gbase = img << 18;

    ull E[8], W[8], S[8], F[8];
    for (int q = 0; q < 8; ++q) {
        ull ea = 0, wa = 0, sa = 0, fa = 0;
        for (int y = 0; y < 64; ++y) {
            float v = state[gbase + ((row0 + y) << 9) + (q << 6) + lane];
            int c = (int)v;
            int cd = c & 15;
            ull eb = __ballot(cd == 3 || cd == 2);
            ull wbt = __ballot(cd == 1 || cd == 2);
            ull sb = __ballot(cd == 3);
            ull fb = __ballot((c & FRAG_BIT) != 0);
            if (lane == y) { ea = eb; wa = wbt; sa = sb; fa = fb; }
        }
        E[q] = ea; W[q] = wa; S[q] = sa; F[q] = fa;
    }

    bool sweep_changed = false;
    int rT = (row0 + 511) & 511;
    int rB = (row0 + 64) & 511;

    for (int r = 0; r < NREFRESH_FB; ++r) {
        ull tT[8], tB[8], HT[8], HB[8];
#pragma unroll
        for (int q = 0; q < 8; ++q) {
            int cdT = ((int)state[gbase + (rT << 9) + (q << 6) + lane]) & 15;
            tT[q] = __ballot(cdT == 3 || cdT == 2);
            int cdB = ((int)state[gbase + (rB << 9) + (q << 6) + lane]) & 15;
            tB[q] = __ballot(cdB == 3 || cdB == 2);
        }
#pragma unroll
        for (int q = 0; q < 8; ++q) {
            HT[q] = tT[q] | (tT[q] << 1) | (tT[(q + 7) & 7] >> 63)
                  | (tT[q] >> 1) | (tT[(q + 1) & 7] << 63);
            HB[q] = tB[q] | (tB[q] << 1) | (tB[(q + 7) & 7] >> 63)
                  | (tB[q] >> 1) | (tB[(q + 1) & 7] << 63);
        }
        while (true) {
            ull ch = 0;
            ull H[8];
#pragma unroll
            for (int q = 0; q < 8; ++q) {
                H[q] = E[q] | (E[q] << 1) | (E[(q + 7) & 7] >> 63)
                     | (E[q] >> 1) | (E[(q + 1) & 7] << 63);
            }
#pragma unroll
            for (int q = 0; q < 8; ++q) {
                ull up = __shfl_up(H[q], 1);
                ull dn = __shfl_down(H[q], 1);
                if (lane == 0)  up = HT[q];
                if (lane == 63) dn = HB[q];
                ull nbr = H[q] | up | dn;
                ull nw = E[q] | (W[q] & nbr);
                ch |= nw ^ E[q];
                E[q] = nw;
            }
            if (!__any(ch != 0)) break;
            sweep_changed = true;
        }
#pragma unroll
        for (int rr = 0; rr < 2; ++rr) {
            int y = rr ? 63 : 0;
#pragma unroll
            for (int q = 0; q < 8; ++q) {
                ull Ew = __shfl(E[q], y), Sw = __shfl(S[q], y);
                ull Ww = __shfl(W[q], y), Fw = __shfl(F[q], y);
                int cd = (int)((Sw >> lane) & 1) ? 3
                       : ((int)((Ew >> lane) & 1) ? 2
                       : ((int)((Ww >> lane) & 1) ? 1 : 0));
                int fl = (int)((Fw >> lane) & 1) ? FRAG_BIT : 0;
                state[gbase + ((row0 + y) << 9) + (q << 6) + lane] = (float)(cd + fl);
            }
        }
        __threadfence();
    }

    for (int y = 0; y < 64; ++y) {
#pragma unroll
        for (int q = 0; q < 8; ++q) {
            ull Ew = __shfl(E[q], y), Sw = __shfl(S[q], y);
            ull Ww = __shfl(W[q], y), Fw = __shfl(F[q], y);
            int cd = (int)((Sw >> lane) & 1) ? 3
                   : ((int)((Ew >> lane) & 1) ? 2
                   : ((int)((Ww >> lane) & 1) ? 1 : 0));
            int fl = (int)((Fw >> lane) & 1) ? FRAG_BIT : 0;
            state[gbase + ((row0 + y) << 9) + (q << 6) + lane] = (float)(cd + fl);
        }
    }
    if (use_flags && sweep_changed && lane == 0)
        atomicAdd(&flags[k], 1u);
}

__global__ __launch_bounds__(256) void finalize_kernel(float* __restrict__ state)
{
    int i = blockIdx.x * 256 + threadIdx.x;
    int cd = ((int)state[i]) & 15;
    float o;
    if (cd == 3)      o = 1.0078125f;
    else if (cd == 2) o = 0.9921875f;
    else if (cd == 1) o = 0.01171875f;
    else              o = 0.00390625f;
    state[i] = o;
}

extern "C" void kernel_launch(void* const* d_in, const int* in_sizes, int n_in,
                              void* d_out, int out_size, void* d_ws, size_t ws_size,
                              hipStream_t stream)
{
    const float* x = nullptr;
    const float* k3[3] = { nullptr, nullptr, nullptr };
    int nk = 0;
    for (int i = 0; i < n_in; ++i) {
        if (in_sizes[i] == NPIX) x = (const float*)d_in[i];
        else if (in_sizes[i] == 9 && nk < 3) k3[nk++] = (const float*)d_in[i];
    }
    float* state = (float*)d_out;
    char* ws = (char*)d_ws;

    int meta_ok = (ws_size >= (size_t)WS_META_MIN) ? 1 : 0;
    int mag_ok  = (ws_size >= WS_EMASK) ? 1 : 0;
    int mask_ok = (ws_size >= WS_MASK_END) ? 1 : 0;
    int full_ok = (ws_size >= WS_FULL_END) ? 1 : 0;
    unsigned int* flags = (unsigned int*)(ws + WS_FLAGS);
    unsigned int* hdr   = (unsigned int*)(ws + WS_HDR);
    unsigned int* list  = (unsigned int*)(ws + WS_LIST);
    float* magbuf  = (float*)(ws + WS_MAG);
    ull* Em = (ull*)(ws + WS_EMASK);
    ull* Wm = (ull*)(ws + WS_WMASK);
    float* blurbuf = (float*)(ws + WS_BLUR);
    float* angbuf  = (float*)(ws + WS_ANG);
    ull* Sm = (ull*)(ws + WS_SMASK);

    if (full_ok) {
        blur_kernel<<<NPIX / 1024, 256, 0, stream>>>(x, k3[0], k3[1], k3[2],
                                                     blurbuf, (unsigned int*)ws);
        maggrad_kernel<<<NPIX / 1024, 256, 0, stream>>>(blurbuf, k3[0], k3[1], k3[2],
                                                        magbuf, angbuf);
        canny_nms_fast4<<<NPIX / 256, 256, 0, stream>>>(magbuf, angbuf, Em, Sm, Wm, hdr, list);
        frag_apply<<<1, 64, 0, stream>>>(state, hdr, list, Em, Sm, Wm, 2);
        for (int k = 0; k < NSWEEP; ++k)
            hyst_mask<<<128, 64, 0, stream>>>(Em, Wm, flags, k);
        unpack_finalize_masks<<<NPIX / 1024, 256, 0, stream>>>(Em, Sm, Wm, state);
        return;
    }

    if (meta_ok)
        hipMemsetAsync(ws, 0, 1152, stream);

    if (mag_ok) {
        mag_kernel<<<NPIX / 256, 256, 0, stream>>>(x, k3[0], k3[1], k3[2], magbuf);
        canny_nms_fast<<<NPIX / 256, 256, 0, stream>>>(x, k3[0], k3[1], k3[2], magbuf, state);
    } else {
        canny_nms<<<NPIX / 256, 256, 0, stream>>>(x, k3[0], k3[1], k3[2], state);
    }

    if (meta_ok) {
        frag_collect<<<NPIX / 256, 256, 0, stream>>>(state, hdr, list);
        frag_apply<<<1, 64, 0, stream>>>(state, hdr, list, Em, Sm, Wm, mask_ok ? 1 : 0);
    } else {
        resolve_pre<<<1, 256, 0, stream>>>(state);
    }

    if (mask_ok) {
        pack_masks<<<NWORDS / 4, 256, 0, stream>>>(state, Em, Wm);
        for (int k = 0; k < NSWEEP; ++k)
            hyst_mask<<<128, 64, 0, stream>>>(Em, Wm, flags, k);
        unpack_finalize<<<NPIX / 256, 256, 0, stream>>>(Em, state);
    } else {
        for (int k = 0; k < NSWEEP_FB; ++k)
            hyst_bits<<<128, 64, 0, stream>>>(state, flags, k, meta_ok);
        finalize_kernel<<<NPIX / 256, 256, 0, stream>>>(state);
    }
}

// Round 24
// 124.566 us; speedup vs baseline: 1.0646x; 1.0646x over previous
//
#include <hip/hip_runtime.h>
#include <math.h>

typedef unsigned long long ull;

#define NPIX (16 * 512 * 512)   // 4,194,304 pixels
#define NWORDS (NPIX / 64)      // 65,536 u64 row-words
#define NSWEEP 4
#define NREFRESH 20
#define NSWEEP_FB 16
#define NREFRESH_FB 16
#define FRAG_BIT 16

// ---- resolved fragile ranks (ascending-pixel-index order, frozen) ----
__device__ __constant__ int REF0_RANKS[3] = { 0, 1, 3 };
#define N_REF0 3

// ---- d_ws layout (tier-gated on ws_size) ----
#define WS_FLAGS    0
#define WS_HDR      96
#define WS_LIST     128
#define WS_META_MIN 8192
#define WS_MAG      8192                                     // NPIX f32
#define WS_EMASK    (8192 + (size_t)NPIX * 4)                // NWORDS u64
#define WS_WMASK    (WS_EMASK + (size_t)NWORDS * 8)          // NWORDS u64
#define WS_MASK_END (WS_WMASK + (size_t)NWORDS * 8)
#define WS_BLUR     WS_MASK_END                              // NPIX f32
#define WS_ANG      (WS_BLUR + (size_t)NPIX * 4)             // NPIX f32
#define WS_SMASK    (WS_ANG + (size_t)NPIX * 4)              // NWORDS u64
#define WS_FULL_END (WS_SMASK + (size_t)NWORDS * 8)

// ---- frozen arithmetic (R12): stage-rounded conv, f32 mag, CR atan2 ----
__device__ inline void grad_sr(const float* __restrict__ xb, int h, int w,
                               const double* g, const double* sxk, const double* syk,
                               float& gx, float& gy)
{
    float pat[5][5];
#pragma unroll
    for (int dy = 0; dy < 5; ++dy) {
        int hh = h + dy - 2;
        bool hv = (unsigned)hh < 512u;
#pragma unroll
        for (int dx = 0; dx < 5; ++dx) {
            int ww = w + dx - 2;
            pat[dy][dx] = (hv && (unsigned)ww < 512u) ? xb[(hh << 9) + ww] : 0.0f;
        }
    }
    float bl[3][3];
#pragma unroll
    for (int by = 0; by < 3; ++by) {
#pragma unroll
        for (int bx = 0; bx < 3; ++bx) {
            int hh = h + by - 1, ww = w + bx - 1;
            if ((unsigned)hh < 512u && (unsigned)ww < 512u) {
                double acc = 0.0;
#pragma unroll
                for (int i = 0; i < 3; ++i)
#pragma unroll
                    for (int j = 0; j < 3; ++j)
                        acc += g[i * 3 + j] * (double)pat[by + i][bx + j];
                bl[by][bx] = (float)acc;
            } else bl[by][bx] = 0.0f;
        }
    }
    double ax = 0.0, ay = 0.0;
#pragma unroll
    for (int i = 0; i < 3; ++i)
#pragma unroll
        for (int j = 0; j < 3; ++j) {
            double b = (double)bl[i][j];
            ax += sxk[i * 3 + j] * b;
            ay += syk[i * 3 + j] * b;
        }
    gx = (float)ax; gy = (float)ay;
}

__device__ inline float mag_sr(const float* __restrict__ xb, int h, int w,
                               const double* g, const double* sxk, const double* syk)
{
    float gx, gy;
    grad_sr(xb, h, w, g, sxk, syk, gx, gy);
    return __fsqrt_rn(__fadd_rn(__fmul_rn(gx, gx), __fmul_rn(gy, gy)));
}

__device__ inline void kernel_id(const float* kA, const float* kB, const float* kC,
                                 const float*& gkf, const float*& sxf, const float*& syf)
{
    const float* ks[3] = { kA, kB, kC };
    gkf = nullptr; sxf = nullptr; syf = nullptr;
    for (int c = 0; c < 3; ++c) {
        const float* k = ks[c];
        float mn = k[0];
#pragma unroll
        for (int q = 1; q < 9; ++q) mn = fminf(mn, k[q]);
        if (mn >= 0.0f)              gkf = k;
        else if (fabsf(k[1]) < 0.5f) sxf = k;
        else                         syf = k;
    }
    if (!gkf || !sxf || !syf) { gkf = kA; sxf = kB; syf = kC; }
}

// Hybrid angle (R21): atan2f when provably >1e-3 deg from every bucket
// boundary (f32 err ~2e-4 deg -> same bucket as CR, fragA provably false
// since 3e-5 << 1e-3); frozen f64-CR otherwise.
__device__ inline float hyb_angle(float gx, float gy)
{
    const float C = (float)(180.0 / 3.14159);
    float angf = __fmul_rn(atan2f(gy, gx), C);
    if (angf < 0.0f) angf = __fadd_rn(angf, 180.0f);
    float dB = fminf(fminf(fabsf(angf - 22.5f), fabsf(angf - 67.5f)),
                     fminf(fabsf(angf - 112.5f), fabsf(angf - 157.5f)));
    if (dB > 1e-3f) return angf;
    float dir = (float)atan2((double)gy, (double)gx);
    float ang = __fmul_rn(dir, C);
    if (ang < 0.0f) ang = __fadd_rn(ang, 180.0f);
    return ang;
}

// Core decision given the final angle (frozen semantics R13-R23).
__device__ inline int nms_decide_core(float m, float ang,
                                      float mR, float mL, float mD, float mU,
                                      float mDL, float mUR, float mDR, float mUL)
{
    bool k0   = (m >= mR)  && (m >= mL);
    bool k45  = (m >= mDL) && (m >= mUR);
    bool k90  = (m >= mD)  && (m >= mU);
    bool k135 = (m >= mDR) && (m >= mUL);

    int bucket = (ang <= 22.5f || ang > 157.5f) ? 0
               : (ang <= 67.5f) ? 1 : (ang <= 112.5f) ? 2 : 3;
    bool keep = (bucket == 0) ? k0 : (bucket == 1) ? k45 : (bucket == 2) ? k90 : k135;
    float n1m = (bucket == 0) ? mR : (bucket == 1) ? mDL : (bucket == 2) ? mD : mDR;
    float n2m = (bucket == 0) ? mL : (bucket == 1) ? mUR : (bucket == 2) ? mU : mUL;

    int code = (keep && m >= 0.3f) ? 3 : ((keep && m >= 0.1f) ? 1 : 0);

    float tie_eps = fmaxf(3e-7f * m, 2.4e-7f);
    bool tie1 = fabsf(m - n1m) <= tie_eps;
    bool tie2 = fabsf(m - n2m) <= tie_eps;
    bool keep1 = (m >= n1m), keep2 = (m >= n2m);
    bool keepish = (keep1 || tie1) && (keep2 || tie2);
    bool bandok = (m >= 0.1f - 3e-7f);
    bool fragTie = bandok && ((tie1 && (keep2 || tie2)) || (tie2 && (keep1 || tie1)));
    bool fragT = keepish && ((fabsf(m - 0.3f) <= 6e-7f) || (fabsf(m - 0.1f) <= 3e-7f));

    float d225 = fabsf(ang - 22.5f), d675 = fabsf(ang - 67.5f);
    float d1125 = fabsf(ang - 112.5f), d1575 = fabsf(ang - 157.5f);
    float aB = fminf(fminf(d225, d675), fminf(d1125, d1575));
    bool fragA = false;
    if (aB <= 3e-5f && bandok) {
        bool lo, hi;
        if (d225 == aB)       { lo = k0;   hi = k45; }
        else if (d675 == aB)  { lo = k45;  hi = k90; }
        else if (d1125 == aB) { lo = k90;  hi = k135; }
        else                  { lo = k135; hi = k0; }
        fragA = (lo != hi);
    }
    int flag = (fragTie || fragT || fragA) ? FRAG_BIT : 0;
    return code + flag;
}

__device__ inline int nms_decide(float m, float gx, float gy,
                                 float mR, float mL, float mD, float mU,
                                 float mDL, float mUR, float mDR, float mUL)
{
    float dir = (float)atan2((double)gy, (double)gx);
    const float C = (float)(180.0 / 3.14159);
    float ang = __fmul_rn(dir, C);
    if (ang < 0.0f) ang = __fadd_rn(ang, 180.0f);
    return nms_decide_core(m, ang, mR, mL, mD, mU, mDL, mUR, mDR, mUL);
}

// ============ TIER A: blur(+meta zero) -> maggrad(ang) -> nms ============
// blur: 4 consecutive pixels per thread; results buffered and stored as ONE
// aligned float4 (R23's scalar strided stores caused 3.5x write amplification).
__global__ __launch_bounds__(256) void blur_kernel(const float* __restrict__ x,
                                                   const float* __restrict__ kA,
                                                   const float* __restrict__ kB,
                                                   const float* __restrict__ kC,
                                                   float* __restrict__ blur,
                                                   unsigned int* __restrict__ meta)
{
    if (blockIdx.x == 0 && threadIdx.x < 288)
        meta[threadIdx.x] = 0u;

    int i0 = (blockIdx.x * 256 + threadIdx.x) * 4;
    if (i0 >= NPIX) return;
    int h = (i0 >> 9) & 511;
    const float* xb = x + ((i0 >> 18) << 18);

    const float *gkf, *sxf, *syf;
    kernel_id(kA, kB, kC, gkf, sxf, syf);
    double g[9];
#pragma unroll
    for (int k = 0; k < 9; ++k) g[k] = (double)gkf[k];

    float4 ov;
    float* op = (float*)&ov;
#pragma unroll
    for (int p = 0; p < 4; ++p) {
        int w = (i0 + p) & 511;
        double acc = 0.0;
#pragma unroll
        for (int di = 0; di < 3; ++di) {
            int hh = h + di - 1;
            bool hv = (unsigned)hh < 512u;
#pragma unroll
            for (int dj = 0; dj < 3; ++dj) {
                int ww = w + dj - 1;
                float v = (hv && (unsigned)ww < 512u) ? xb[(hh << 9) + ww] : 0.0f;
                acc += g[di * 3 + dj] * (double)v;
            }
        }
        op[p] = (float)acc;
    }
    *(float4*)(blur + i0) = ov;
}

// maggrad: 4 pixels/thread; ONE float4 store each for mag and ang.
__global__ __launch_bounds__(256) void maggrad_kernel(const float* __restrict__ blur,
                                                      const float* __restrict__ kA,
                                                      const float* __restrict__ kB,
                                                      const float* __restrict__ kC,
                                                      float* __restrict__ mag,
                                                      float* __restrict__ angb)
{
    int i0 = (blockIdx.x * 256 + threadIdx.x) * 4;
    if (i0 >= NPIX) return;
    int h = (i0 >> 9) & 511;
    int pb = (i0 >> 18) << 18;

    const float *gkf, *sxf, *syf;
    kernel_id(kA, kB, kC, gkf, sxf, syf);
    double sxk[9], syk[9];
#pragma unroll
    for (int k = 0; k < 9; ++k) { sxk[k] = (double)sxf[k]; syk[k] = (double)syf[k]; }

    float4 mv, av;
    float* mp = (float*)&mv;
    float* ap = (float*)&av;
#pragma unroll
    for (int p = 0; p < 4; ++p) {
        int w = (i0 + p) & 511;
        double ax = 0.0, ay = 0.0;
#pragma unroll
        for (int di = 0; di < 3; ++di) {
            int hh = h + di - 1;
            bool hv = (unsigned)hh < 512u;
#pragma unroll
            for (int dj = 0; dj < 3; ++dj) {
                int ww = w + dj - 1;
                double b = (hv && (unsigned)ww < 512u)
                         ? (double)blur[pb + (hh << 9) + ww] : 0.0;
                ax += sxk[di * 3 + dj] * b;
                ay += syk[di * 3 + dj] * b;
            }
        }
        float gx = (float)ax, gy = (float)ay;
        mp[p] = __fsqrt_rn(__fadd_rn(__fmul_rn(gx, gx), __fmul_rn(gy, gy)));
        ap[p] = hyb_angle(gx, gy);
    }
    *(float4*)(mag + i0) = mv;
    *(float4*)(angb + i0) = av;
}

// stage-3: pure-memory NMS decision from mag + ang
__global__ __launch_bounds__(256) void canny_nms_fast4(const float* __restrict__ mag,
                                                       const float* __restrict__ angb,
                                                       ull* __restrict__ Em,
                                                       ull* __restrict__ Sm,
                                                       ull* __restrict__ Wm,
                                                       unsigned int* __restrict__ hdr,
                                                       unsigned int* __restrict__ list)
{
    int i = blockIdx.x * 256 + threadIdx.x;
    if (i >= NPIX) return;
    int w = i & 511;
    int h = (i >> 9) & 511;
    int pb = (i >> 18) << 18;

    float m = mag[i];
    float ang = angb[i];

    int hp = (h + 1) & 511, hm = (h - 1) & 511;
    int wp = (w + 1) & 511, wm = (w - 1) & 511;

    float mR  = mag[pb + (h  << 9) + wp];
    float mL  = mag[pb + (h  << 9) + wm];
    float mD  = mag[pb + (hp << 9) + w ];
    float mU  = mag[pb + (hm << 9) + w ];
    float mDL = mag[pb + (hp << 9) + wm];
    float mUR = mag[pb + (hm << 9) + wp];
    float mDR = mag[pb + (hp << 9) + wp];
    float mUL = mag[pb + (hm << 9) + wm];

    int cv = nms_decide_core(m, ang, mR, mL, mD, mU, mDL, mUR, mDR, mUL);
    int cd = cv & 15;

    ull eb = __ballot(cd == 3);
    ull wb = __ballot(cd == 1);
    if ((threadIdx.x & 63) == 0) {
        Em[i >> 6] = eb; Sm[i >> 6] = eb; Wm[i >> 6] = wb;
    }
    if (cv & FRAG_BIT) {
        unsigned int p = atomicAdd(hdr, 1u);
        if (p < 256u) list[p] = (unsigned int)i;
    }
}

// ============ TIER B fallbacks ============

__global__ __launch_bounds__(256) void canny_nms(const float* __restrict__ x,
                                                 const float* __restrict__ kA,
                                                 const float* __restrict__ kB,
                                                 const float* __restrict__ kC,
                                                 float* __restrict__ state)
{
    int i = blockIdx.x * 256 + threadIdx.x;
    if (i >= NPIX) return;
    int w = i & 511;
    int h = (i >> 9) & 511;
    const float* xb = x + ((i >> 18) << 18);

    const float *gkf, *sxf, *syf;
    kernel_id(kA, kB, kC, gkf, sxf, syf);
    double g[9], sxk[9], syk[9];
#pragma unroll
    for (int k = 0; k < 9; ++k) {
        g[k] = (double)gkf[k]; sxk[k] = (double)sxf[k]; syk[k] = (double)syf[k];
    }

    float gx, gy;
    grad_sr(xb, h, w, g, sxk, syk, gx, gy);
    float m = __fsqrt_rn(__fadd_rn(__fmul_rn(gx, gx), __fmul_rn(gy, gy)));

    int hp = (h + 1) & 511, hm = (h - 1) & 511;
    int wp = (w + 1) & 511, wm = (w - 1) & 511;

    float mR  = mag_sr(xb, h,  wp, g, sxk, syk);
    float mL  = mag_sr(xb, h,  wm, g, sxk, syk);
    float mD  = mag_sr(xb, hp, w,  g, sxk, syk);
    float mU  = mag_sr(xb, hm, w,  g, sxk, syk);
    float mDL = mag_sr(xb, hp, wm, g, sxk, syk);
    float mUR = mag_sr(xb, hm, wp, g, sxk, syk);
    float mDR = mag_sr(xb, hp, wp, g, sxk, syk);
    float mUL = mag_sr(xb, hm, wm, g, sxk, syk);

    state[i] = (float)nms_decide(m, gx, gy, mR, mL, mD, mU, mDL, mUR, mDR, mUL);
}

__global__ __launch_bounds__(256) void mag_kernel(const float* __restrict__ x,
                                                  const float* __restrict__ kA,
                                                  const float* __restrict__ kB,
                                                  const float* __restrict__ kC,
                                                  float* __restrict__ mag)
{
    int i = blockIdx.x * 256 + threadIdx.x;
    if (i >= NPIX) return;
    int w = i & 511;
    int h = (i >> 9) & 511;
    const float* xb = x + ((i >> 18) << 18);

    const float *gkf, *sxf, *syf;
    kernel_id(kA, kB, kC, gkf, sxf, syf);
    double g[9], sxk[9], syk[9];
#pragma unroll
    for (int k = 0; k < 9; ++k) {
        g[k] = (double)gkf[k]; sxk[k] = (double)sxf[k]; syk[k] = (double)syf[k];
    }
    mag[i] = mag_sr(xb, h, w, g, sxk, syk);
}

__global__ __launch_bounds__(256) void canny_nms_fast(const float* __restrict__ x,
                                                      const float* __restrict__ kA,
                                                      const float* __restrict__ kB,
                                                      const float* __restrict__ kC,
                                                      const float* __restrict__ mag,
                                                      float* __restrict__ state)
{
    int i = blockIdx.x * 256 + threadIdx.x;
    if (i >= NPIX) return;
    int w = i & 511;
    int h = (i >> 9) & 511;
    int pb = (i >> 18) << 18;
    const float* xb = x + pb;

    const float *gkf, *sxf, *syf;
    kernel_id(kA, kB, kC, gkf, sxf, syf);
    double g[9], sxk[9], syk[9];
#pragma unroll
    for (int k = 0; k < 9; ++k) {
        g[k] = (double)gkf[k]; sxk[k] = (double)sxf[k]; syk[k] = (double)syf[k];
    }

    float gx, gy;
    grad_sr(xb, h, w, g, sxk, syk, gx, gy);
    float m = mag[i];

    int hp = (h + 1) & 511, hm = (h - 1) & 511;
    int wp = (w + 1) & 511, wm = (w - 1) & 511;

    float mR  = mag[pb + (h  << 9) + wp];
    float mL  = mag[pb + (h  << 9) + wm];
    float mD  = mag[pb + (hp << 9) + w ];
    float mU  = mag[pb + (hm << 9) + w ];
    float mDL = mag[pb + (hp << 9) + wm];
    float mUR = mag[pb + (hm << 9) + wp];
    float mDR = mag[pb + (hp << 9) + wp];
    float mUL = mag[pb + (hm << 9) + wm];

    state[i] = (float)nms_decide(m, gx, gy, mR, mL, mD, mU, mDL, mUR, mDR, mUL);
}

__global__ __launch_bounds__(256) void frag_collect(const float* __restrict__ state,
                                                    unsigned int* __restrict__ hdr,
                                                    unsigned int* __restrict__ list)
{
    int i = blockIdx.x * 256 + threadIdx.x;
    if (i >= NPIX) return;
    if (((int)state[i]) & FRAG_BIT) {
        unsigned int p = atomicAdd(hdr, 1u);
        if (p < 256u) list[p] = (unsigned int)i;
    }
}

// mode: 0 = state only; 1 = state + Em/Wm; 2 = masks Em/Sm/Wm (tier A)
__global__ void frag_apply(float* __restrict__ state,
                           const unsigned int* __restrict__ hdr,
                           const unsigned int* __restrict__ list,
                           ull* __restrict__ Em,
                           ull* __restrict__ Sm,
                           ull* __restrict__ Wm,
                           int mode)
{
    __shared__ unsigned int sl[256];
    __shared__ int sn;
    int t = threadIdx.x;
    if (t == 0) { unsigned int hv = *hdr; sn = (hv < 256u) ? (int)hv : 256; }
    __syncthreads();
    int n = sn;
    for (int j = t; j < n; j += 64) sl[j] = list[j];
    __syncthreads();
    if (t == 0) {
        for (int a = 0; a < n - 1; ++a) {
            int mi = a;
            for (int b = a + 1; b < n; ++b) if (sl[b] < sl[mi]) mi = b;
            unsigned int tmp = sl[a]; sl[a] = sl[mi]; sl[mi] = tmp;
        }
    }
    __syncthreads();
    for (int j = t; j < n; j += 64) {
        bool r0 = false;
        for (int q = 0; q < N_REF0; ++q) if (REF0_RANKS[q] == j) r0 = true;
        unsigned int px = sl[j];
        if (mode != 2)
            state[px] = r0 ? (float)FRAG_BIT : (float)(FRAG_BIT + 3);
        if (mode >= 1) {
            ull bit = 1ull << (px & 63);
            if (r0) atomicAnd(&Em[px >> 6], ~bit);
            else    atomicOr(&Em[px >> 6], bit);
            atomicAnd(&Wm[px >> 6], ~bit);
            if (mode == 2) {
                if (r0) atomicAnd(&Sm[px >> 6], ~bit);
                else    atomicOr(&Sm[px >> 6], bit);
            }
        }
    }
}

__global__ void resolve_pre(float* __restrict__ state)
{
    __shared__ int cnt[256];
    __shared__ int base[256];
    int t = threadIdx.x;
    const int chunk = NPIX / 256;
    int lo = t * chunk, hi2 = lo + chunk;
    int c = 0;
    for (int p = lo; p < hi2; ++p)
        if (((int)state[p]) & FRAG_BIT) ++c;
    cnt[t] = c;
    __syncthreads();
    if (t == 0) {
        int s = 0;
        for (int q = 0; q < 256; ++q) { base[q] = s; s += cnt[q]; }
    }
    __syncthreads();
    int j = base[t];
    for (int p = lo; p < hi2; ++p) {
        int cv = (int)state[p];
        if (cv & FRAG_BIT) {
            bool res0 = false;
            for (int q = 0; q < N_REF0; ++q) if (REF0_RANKS[q] == j) res0 = true;
            state[p] = res0 ? (float)FRAG_BIT : (float)(FRAG_BIT + 3);
            ++j;
        }
    }
}

__global__ __launch_bounds__(256) void pack_masks(const float* __restrict__ state,
                                                  ull* __restrict__ Em,
                                                  ull* __restrict__ Wm)
{
    int wv = blockIdx.x * 4 + (threadIdx.x >> 6);
    int lane = threadIdx.x & 63;
    int i = (wv << 6) + lane;
    int cd = ((int)state[i]) & 15;
    ull eb = __ballot(cd == 3);
    ull wb = __ballot(cd == 1);
    if (lane == 0) { Em[wv] = eb; Wm[wv] = wb; }
}

__device__ inline void hfill(ull* E, const ull* W)
{
#pragma unroll
    for (int pass = 0; pass < 2; ++pass) {
        ull cin = (E[7] >> 63) & 1ull;
#pragma unroll
        for (int q = 0; q < 8; ++q) {
            ull S = E[q] & W[q];
            ull sum = W[q] + (S << 1) + cin;
            E[q] |= W[q] & (W[q] ^ sum);
            cin = (E[q] >> 63) & 1ull;
        }
    }
    ull RE[8], RW[8];
#pragma unroll
    for (int q = 0; q < 8; ++q) {
        RE[q] = __builtin_bitreverse64(E[7 - q]);
        RW[q] = __builtin_bitreverse64(W[7 - q]);
    }
#pragma unroll
    for (int pass = 0; pass < 2; ++pass) {
        ull cin = (RE[7] >> 63) & 1ull;
#pragma unroll
        for (int q = 0; q < 8; ++q) {
            ull S = RE[q] & RW[q];
            ull sum = RW[q] + (S << 1) + cin;
            RE[q] |= RW[q] & (RW[q] ^ sum);
            cin = (RE[q] >> 63) & 1ull;
        }
    }
#pragma unroll
    for (int q = 0; q < 8; ++q)
        E[q] = __builtin_bitreverse64(RE[7 - q]);
}

__global__ __launch_bounds__(64) void hyst_mask(ull* __restrict__ Em,
                                                const ull* __restrict__ Wm,
                                                unsigned int* __restrict__ flags,
                                                int k)
{
    if (k > 0 && flags[k - 1] == 0u) return;
    int strip = blockIdx.x;
    int img = strip >> 3;
    int s = strip & 7;
    int lane = threadIdx.x;
    int row0 = s << 6;
    int wb = img * 4096 + (row0 + lane) * 8;
    int wT = img * 4096 + (((row0 + 511) & 511) * 8);
    int wB = img * 4096 + (((row0 + 64) & 511) * 8);

    ull E[8], W[8];
#pragma unroll
    for (int q = 0; q < 8; ++q) { E[q] = Em[wb + q]; W[q] = Wm[wb + q]; }

    bool sweep_changed = false;
    bool first = true;
    ull prevH[8] = {0,0,0,0,0,0,0,0};

    for (int r = 0; r < NREFRESH; ++r) {
        ull HL[8] = {0,0,0,0,0,0,0,0};
        if (lane == 0) {
#pragma unroll
            for (int q = 0; q < 8; ++q) HL[q] = Em[wT + q];
        } else if (lane == 63) {
#pragma unroll
            for (int q = 0; q < 8; ++q) HL[q] = Em[wB + q];
        }
        bool hch = first;
#pragma unroll
        for (int q = 0; q < 8; ++q) { hch |= (HL[q] != prevH[q]); prevH[q] = HL[q]; }
        first = false;
        if (!__any(hch)) break;

        ull HS[8];
#pragma unroll
        for (int q = 0; q < 8; ++q) {
            HS[q] = HL[q] | (HL[q] << 1) | (HL[(q + 7) & 7] >> 63)
                  | (HL[q] >> 1) | (HL[(q + 1) & 7] << 63);
        }
        while (true) {
            ull ch = 0;
            ull H[8];
#pragma unroll
            for (int q = 0; q < 8; ++q) {
                H[q] = E[q] | (E[q] << 1) | (E[(q + 7) & 7] >> 63)
                     | (E[q] >> 1) | (E[(q + 1) & 7] << 63);
            }
            ull En[8];
#pragma unroll
            for (int q = 0; q < 8; ++q) {
                ull up = __shfl_up(H[q], 1);
                ull dn = __shfl_down(H[q], 1);
                if (lane == 0)  up = HS[q];
                if (lane == 63) dn = HS[q];
                En[q] = E[q] | (W[q] & (H[q] | up | dn));
            }
            hfill(En, W);
#pragma unroll
            for (int q = 0; q < 8; ++q) { ch |= En[q] ^ E[q]; E[q] = En[q]; }
            if (!__any(ch != 0)) break;
            sweep_changed = true;
        }
        if (lane == 0 || lane == 63) {
#pragma unroll
            for (int q = 0; q < 8; ++q) Em[wb + q] = E[q];
        }
        __threadfence();
    }

#pragma unroll
    for (int q = 0; q < 8; ++q) Em[wb + q] = E[q];
    if (sweep_changed && lane == 0)
        atomicAdd(&flags[k], 1u);
}

// tier-A finalize: 4 pixels/thread, float4 store
__global__ __launch_bounds__(256) void unpack_finalize_masks(const ull* __restrict__ Em,
                                                             const ull* __restrict__ Sm,
                                                             const ull* __restrict__ Wm,
                                                             float* __restrict__ out)
{
    int i0 = (blockIdx.x * 256 + threadIdx.x) * 4;
    if (i0 >= NPIX) return;
    int wv = i0 >> 6, sh = i0 & 63;   // 4 pixels share one word (sh <= 60)
    ull e4 = Em[wv] >> sh;
    ull s4 = Sm[wv] >> sh;
    ull w4 = Wm[wv] >> sh;
    float4 o;
    float* op = (float*)&o;
#pragma unroll
    for (int p = 0; p < 4; ++p) {
        int e = (int)((e4 >> p) & 1ull);
        int s = (int)((s4 >> p) & 1ull);
        int wk = (int)((w4 >> p) & 1ull);
        op[p] = e ? (s ? 1.0078125f : 0.9921875f)
                  : (wk ? 0.01171875f : 0.00390625f);
    }
    *(float4*)(out + i0) = o;
}

__global__ __launch_bounds__(256) void unpack_finalize(const ull* __restrict__ Em,
                                                       float* __restrict__ state)
{
    int i = blockIdx.x * 256 + threadIdx.x;
    int cd = ((int)state[i]) & 15;
    int e = (int)((Em[i >> 6] >> (i & 63)) & 1ull);
    float o;
    if (e)           o = (cd == 3) ? 1.0078125f : 0.9921875f;
    else             o = (cd == 1) ? 0.01171875f : 0.00390625f;
    state[i] = o;
}

__global__ __launch_bounds__(64) void hyst_bits(float* __restrict__ state,
                                                unsigned int* __restrict__ flags,
                                                int k, int use_flags)
{
    if (use_flags && k > 0) { if (flags[k - 1] == 0u) return; }
    int strip = blockIdx.x;
    int img = strip >> 3;
    int s = strip & 7;
    int lane = threadIdx.x;
    int row0 = s << 6;
    int gbase = img << 18;

    ull E[8], W[8], S[8], F[8];
    for (int q = 0; q < 8; ++q) {
        ull ea = 0, wa = 0, sa = 0, fa = 0;
        for (int y = 0; y < 64; ++y) {
            float v = state[gbase + ((row0 + y) << 9) + (q << 6) + lane];
            int c = (int)v;
            int cd = c & 15;
            ull eb = __ballot(cd == 3 || cd == 2);
            ull wbt = __ballot(cd == 1 || cd == 2);
            ull sb = __ballot(cd == 3);
            ull fb = __ballot((c & FRAG_BIT) != 0);
            if (lane == y) { ea = eb; wa = wbt; sa = sb; fa = fb; }
        }
        E[q] = ea; W[q] = wa; S[q] = sa; F[q] = fa;
    }

    bool sweep_changed = false;
    int rT = (row0 + 511) & 511;
    int rB = (row0 + 64) & 511;

    for (int r = 0; r < NREFRESH_FB; ++r) {
        ull tT[8], tB[8], HT[8], HB[8];
#pragma unroll
        for (int q = 0; q < 8; ++q) {
            int cdT = ((int)state[gbase + (rT << 9) + (q << 6) + lane]) & 15;
            tT[q] = __ballot(cdT == 3 || cdT == 2);
            int cdB = ((int)state[gbase + (rB << 9) + (q << 6) + lane]) & 15;
            tB[q] = __ballot(cdB == 3 || cdB == 2);
        }
#pragma unroll
        for (int q = 0; q < 8; ++q) {
            HT[q] = tT[q] | (tT[q] << 1) | (tT[(q + 7) & 7] >> 63)
                  | (tT[q] >> 1) | (tT[(q + 1) & 7] << 63);
            HB[q] = tB[q] | (tB[q] << 1) | (tB[(q + 7) & 7] >> 63)
                  | (tB[q] >> 1) | (tB[(q + 1) & 7] << 63);
        }
        while (true) {
            ull ch = 0;
            ull H[8];
#pragma unroll
            for (int q = 0; q < 8; ++q) {
                H[q] = E[q] | (E[q] << 1) | (E[(q + 7) & 7] >> 63)
                     | (E[q] >> 1) | (E[(q + 1) & 7] << 63);
            }
#pragma unroll
            for (int q = 0; q < 8; ++q) {
                ull up = __shfl_up(H[q], 1);
                ull dn = __shfl_down(H[q], 1);
                if (lane == 0)  up = HT[q];
                if (lane == 63) dn = HB[q];
                ull nbr = H[q] | up | dn;
                ull nw = E[q] | (W[q] & nbr);
                ch |= nw ^ E[q];
                E[q] = nw;
            }
            if (!__any(ch != 0)) break;
            sweep_changed = true;
        }
#pragma unroll
        for (int rr = 0; rr < 2; ++rr) {
            int y = rr ? 63 : 0;
#pragma unroll
            for (int q = 0; q < 8; ++q) {
                ull Ew = __shfl(E[q], y), Sw = __shfl(S[q], y);
                ull Ww = __shfl(W[q], y), Fw = __shfl(F[q], y);
                int cd = (int)((Sw >> lane) & 1) ? 3
                       : ((int)((Ew >> lane) & 1) ? 2
                       : ((int)((Ww >> lane) & 1) ? 1 : 0));
                int fl = (int)((Fw >> lane) & 1) ? FRAG_BIT : 0;
                state[gbase + ((row0 + y) << 9) + (q << 6) + lane] = (float)(cd + fl);
            }
        }
        __threadfence();
    }

    for (int y = 0; y < 64; ++y) {
#pragma unroll
        for (int q = 0; q < 8; ++q) {
            ull Ew = __shfl(E[q], y), Sw = __shfl(S[q], y);
            ull Ww = __shfl(W[q], y), Fw = __shfl(F[q], y);
            int cd = (int)((Sw >> lane) & 1) ? 3
                   : ((int)((Ew >> lane) & 1) ? 2
                   : ((int)((Ww >> lane) & 1) ? 1 : 0));
            int fl = (int)((Fw >> lane) & 1) ? FRAG_BIT : 0;
            state[gbase + ((row0 + y) << 9) + (q << 6) + lane] = (float)(cd + fl);
        }
    }
    if (use_flags && sweep_changed && lane == 0)
        atomicAdd(&flags[k], 1u);
}

__global__ __launch_bounds__(256) void finalize_kernel(float* __restrict__ state)
{
    int i = blockIdx.x * 256 + threadIdx.x;
    int cd = ((int)state[i]) & 15;
    float o;
    if (cd == 3)      o = 1.0078125f;
    else if (cd == 2) o = 0.9921875f;
    else if (cd == 1) o = 0.01171875f;
    else              o = 0.00390625f;
    state[i] = o;
}

extern "C" void kernel_launch(void* const* d_in, const int* in_sizes, int n_in,
                              void* d_out, int out_size, void* d_ws, size_t ws_size,
                              hipStream_t stream)
{
    const float* x = nullptr;
    const float* k3[3] = { nullptr, nullptr, nullptr };
    int nk = 0;
    for (int i = 0; i < n_in; ++i) {
        if (in_sizes[i] == NPIX) x = (const float*)d_in[i];
        else if (in_sizes[i] == 9 && nk < 3) k3[nk++] = (const float*)d_in[i];
    }
    float* state = (float*)d_out;
    char* ws = (char*)d_ws;

    int meta_ok = (ws_size >= (size_t)WS_META_MIN) ? 1 : 0;
    int mag_ok  = (ws_size >= WS_EMASK) ? 1 : 0;
    int mask_ok = (ws_size >= WS_MASK_END) ? 1 : 0;
    int full_ok = (ws_size >= WS_FULL_END) ? 1 : 0;
    unsigned int* flags = (unsigned int*)(ws + WS_FLAGS);
    unsigned int* hdr   = (unsigned int*)(ws + WS_HDR);
    unsigned int* list  = (unsigned int*)(ws + WS_LIST);
    float* magbuf  = (float*)(ws + WS_MAG);
    ull* Em = (ull*)(ws + WS_EMASK);
    ull* Wm = (ull*)(ws + WS_WMASK);
    float* blurbuf = (float*)(ws + WS_BLUR);
    float* angbuf  = (float*)(ws + WS_ANG);
    ull* Sm = (ull*)(ws + WS_SMASK);

    if (full_ok) {
        blur_kernel<<<NPIX / 1024, 256, 0, stream>>>(x, k3[0], k3[1], k3[2],
                                                     blurbuf, (unsigned int*)ws);
        maggrad_kernel<<<NPIX / 1024, 256, 0, stream>>>(blurbuf, k3[0], k3[1], k3[2],
                                                        magbuf, angbuf);
        canny_nms_fast4<<<NPIX / 256, 256, 0, stream>>>(magbuf, angbuf, Em, Sm, Wm, hdr, list);
        frag_apply<<<1, 64, 0, stream>>>(state, hdr, list, Em, Sm, Wm, 2);
        for (int k = 0; k < NSWEEP; ++k)
            hyst_mask<<<128, 64, 0, stream>>>(Em, Wm, flags, k);
        unpack_finalize_masks<<<NPIX / 1024, 256, 0, stream>>>(Em, Sm, Wm, state);
        return;
    }

    if (meta_ok)
        hipMemsetAsync(ws, 0, 1152, stream);

    if (mag_ok) {
        mag_kernel<<<NPIX / 256, 256, 0, stream>>>(x, k3[0], k3[1], k3[2], magbuf);
        canny_nms_fast<<<NPIX / 256, 256, 0, stream>>>(x, k3[0], k3[1], k3[2], magbuf, state);
    } else {
        canny_nms<<<NPIX / 256, 256, 0, stream>>>(x, k3[0], k3[1], k3[2], state);
    }

    if (meta_ok) {
        frag_collect<<<NPIX / 256, 256, 0, stream>>>(state, hdr, list);
        frag_apply<<<1, 64, 0, stream>>>(state, hdr, list, Em, Sm, Wm, mask_ok ? 1 : 0);
    } else {
        resolve_pre<<<1, 256, 0, stream>>>(state);
    }

    if (mask_ok) {
        pack_masks<<<NWORDS / 4, 256, 0, stream>>>(state, Em, Wm);
        for (int k = 0; k < NSWEEP; ++k)
            hyst_mask<<<128, 64, 0, stream>>>(Em, Wm, flags, k);
        unpack_finalize<<<NPIX / 256, 256, 0, stream>>>(Em, state);
    } else {
        for (int k = 0; k < NSWEEP_FB; ++k)
            hyst_bits<<<128, 64, 0, stream>>>(state, flags, k, meta_ok);
        finalize_kernel<<<NPIX / 256, 256, 0, stream>>>(state);
    }
}

// Round 25
// 86.528 us; speedup vs baseline: 1.5326x; 1.4396x over previous
//
#include <hip/hip_runtime.h>
#include <math.h>

typedef unsigned long long ull;

#define NPIX (16 * 512 * 512)   // 4,194,304 pixels
#define NWORDS (NPIX / 64)      // 65,536 u64 row-words
#define NSWEEP 4
#define NREFRESH 20
#define NSWEEP_FB 16
#define NREFRESH_FB 16
#define FRAG_BIT 16

// ---- resolved fragile ranks (ascending-pixel-index order, frozen) ----
__device__ __constant__ int REF0_RANKS[3] = { 0, 1, 3 };
#define N_REF0 3

// ---- d_ws layout (tier-gated on ws_size) ----
#define WS_FLAGS    0
#define WS_HDR      96
#define WS_LIST     128
#define WS_META_MIN 8192
#define WS_MAG      8192                                     // NPIX f32
#define WS_EMASK    (8192 + (size_t)NPIX * 4)                // NWORDS u64
#define WS_WMASK    (WS_EMASK + (size_t)NWORDS * 8)          // NWORDS u64
#define WS_MASK_END (WS_WMASK + (size_t)NWORDS * 8)
#define WS_BLUR     WS_MASK_END                              // NPIX f32
#define WS_ANG      (WS_BLUR + (size_t)NPIX * 4)             // NPIX f32
#define WS_SMASK    (WS_ANG + (size_t)NPIX * 4)              // NWORDS u64
#define WS_FULL_END (WS_SMASK + (size_t)NWORDS * 8)

// ---- frozen arithmetic (R12): stage-rounded conv, f32 mag, CR atan2 ----
__device__ inline void grad_sr(const float* __restrict__ xb, int h, int w,
                               const double* g, const double* sxk, const double* syk,
                               float& gx, float& gy)
{
    float pat[5][5];
#pragma unroll
    for (int dy = 0; dy < 5; ++dy) {
        int hh = h + dy - 2;
        bool hv = (unsigned)hh < 512u;
#pragma unroll
        for (int dx = 0; dx < 5; ++dx) {
            int ww = w + dx - 2;
            pat[dy][dx] = (hv && (unsigned)ww < 512u) ? xb[(hh << 9) + ww] : 0.0f;
        }
    }
    float bl[3][3];
#pragma unroll
    for (int by = 0; by < 3; ++by) {
#pragma unroll
        for (int bx = 0; bx < 3; ++bx) {
            int hh = h + by - 1, ww = w + bx - 1;
            if ((unsigned)hh < 512u && (unsigned)ww < 512u) {
                double acc = 0.0;
#pragma unroll
                for (int i = 0; i < 3; ++i)
#pragma unroll
                    for (int j = 0; j < 3; ++j)
                        acc += g[i * 3 + j] * (double)pat[by + i][bx + j];
                bl[by][bx] = (float)acc;
            } else bl[by][bx] = 0.0f;
        }
    }
    double ax = 0.0, ay = 0.0;
#pragma unroll
    for (int i = 0; i < 3; ++i)
#pragma unroll
        for (int j = 0; j < 3; ++j) {
            double b = (double)bl[i][j];
            ax += sxk[i * 3 + j] * b;
            ay += syk[i * 3 + j] * b;
        }
    gx = (float)ax; gy = (float)ay;
}

__device__ inline float mag_sr(const float* __restrict__ xb, int h, int w,
                               const double* g, const double* sxk, const double* syk)
{
    float gx, gy;
    grad_sr(xb, h, w, g, sxk, syk, gx, gy);
    return __fsqrt_rn(__fadd_rn(__fmul_rn(gx, gx), __fmul_rn(gy, gy)));
}

__device__ inline void kernel_id(const float* kA, const float* kB, const float* kC,
                                 const float*& gkf, const float*& sxf, const float*& syf)
{
    const float* ks[3] = { kA, kB, kC };
    gkf = nullptr; sxf = nullptr; syf = nullptr;
    for (int c = 0; c < 3; ++c) {
        const float* k = ks[c];
        float mn = k[0];
#pragma unroll
        for (int q = 1; q < 9; ++q) mn = fminf(mn, k[q]);
        if (mn >= 0.0f)              gkf = k;
        else if (fabsf(k[1]) < 0.5f) sxf = k;
        else                         syf = k;
    }
    if (!gkf || !sxf || !syf) { gkf = kA; sxf = kB; syf = kC; }
}

// Hybrid angle (R21): atan2f when provably >1e-3 deg from every bucket
// boundary; frozen f64-CR otherwise.
__device__ inline float hyb_angle(float gx, float gy)
{
    const float C = (float)(180.0 / 3.14159);
    float angf = __fmul_rn(atan2f(gy, gx), C);
    if (angf < 0.0f) angf = __fadd_rn(angf, 180.0f);
    float dB = fminf(fminf(fabsf(angf - 22.5f), fabsf(angf - 67.5f)),
                     fminf(fabsf(angf - 112.5f), fabsf(angf - 157.5f)));
    if (dB > 1e-3f) return angf;
    float dir = (float)atan2((double)gy, (double)gx);
    float ang = __fmul_rn(dir, C);
    if (ang < 0.0f) ang = __fadd_rn(ang, 180.0f);
    return ang;
}

// Core decision given the final angle (frozen semantics R13-R24).
__device__ inline int nms_decide_core(float m, float ang,
                                      float mR, float mL, float mD, float mU,
                                      float mDL, float mUR, float mDR, float mUL)
{
    bool k0   = (m >= mR)  && (m >= mL);
    bool k45  = (m >= mDL) && (m >= mUR);
    bool k90  = (m >= mD)  && (m >= mU);
    bool k135 = (m >= mDR) && (m >= mUL);

    int bucket = (ang <= 22.5f || ang > 157.5f) ? 0
               : (ang <= 67.5f) ? 1 : (ang <= 112.5f) ? 2 : 3;
    bool keep = (bucket == 0) ? k0 : (bucket == 1) ? k45 : (bucket == 2) ? k90 : k135;
    float n1m = (bucket == 0) ? mR : (bucket == 1) ? mDL : (bucket == 2) ? mD : mDR;
    float n2m = (bucket == 0) ? mL : (bucket == 1) ? mUR : (bucket == 2) ? mU : mUL;

    int code = (keep && m >= 0.3f) ? 3 : ((keep && m >= 0.1f) ? 1 : 0);

    float tie_eps = fmaxf(3e-7f * m, 2.4e-7f);
    bool tie1 = fabsf(m - n1m) <= tie_eps;
    bool tie2 = fabsf(m - n2m) <= tie_eps;
    bool keep1 = (m >= n1m), keep2 = (m >= n2m);
    bool keepish = (keep1 || tie1) && (keep2 || tie2);
    bool bandok = (m >= 0.1f - 3e-7f);
    bool fragTie = bandok && ((tie1 && (keep2 || tie2)) || (tie2 && (keep1 || tie1)));
    bool fragT = keepish && ((fabsf(m - 0.3f) <= 6e-7f) || (fabsf(m - 0.1f) <= 3e-7f));

    float d225 = fabsf(ang - 22.5f), d675 = fabsf(ang - 67.5f);
    float d1125 = fabsf(ang - 112.5f), d1575 = fabsf(ang - 157.5f);
    float aB = fminf(fminf(d225, d675), fminf(d1125, d1575));
    bool fragA = false;
    if (aB <= 3e-5f && bandok) {
        bool lo, hi;
        if (d225 == aB)       { lo = k0;   hi = k45; }
        else if (d675 == aB)  { lo = k45;  hi = k90; }
        else if (d1125 == aB) { lo = k90;  hi = k135; }
        else                  { lo = k135; hi = k0; }
        fragA = (lo != hi);
    }
    int flag = (fragTie || fragT || fragA) ? FRAG_BIT : 0;
    return code + flag;
}

__device__ inline int nms_decide(float m, float gx, float gy,
                                 float mR, float mL, float mD, float mU,
                                 float mDL, float mUR, float mDR, float mUL)
{
    float dir = (float)atan2((double)gy, (double)gx);
    const float C = (float)(180.0 / 3.14159);
    float ang = __fmul_rn(dir, C);
    if (ang < 0.0f) ang = __fadd_rn(ang, 180.0f);
    return nms_decide_core(m, ang, mR, mL, mD, mU, mDL, mUR, mDR, mUL);
}

// Load the 6 columns [w0-1, w0+4] of row `rowp` (valid row) into c[6]:
// aligned float4 at w0 (w0 % 4 == 0) + guarded edge scalars (zero-pad).
__device__ inline void load_row6(const float* __restrict__ rowp, int w0, float* c)
{
    float4 v = *(const float4*)(rowp + w0);
    c[1] = v.x; c[2] = v.y; c[3] = v.z; c[4] = v.w;
    c[0] = (w0 > 0)       ? rowp[w0 - 1] : 0.0f;
    c[5] = (w0 + 4 < 512) ? rowp[w0 + 4] : 0.0f;
}

// ============ TIER A: blur(+meta zero) -> maggrad(ang) -> nms ============
// blur: 4 consecutive pixels/thread, coalesced float4 row loads + float4 store.
__global__ __launch_bounds__(256) void blur_kernel(const float* __restrict__ x,
                                                   const float* __restrict__ kA,
                                                   const float* __restrict__ kB,
                                                   const float* __restrict__ kC,
                                                   float* __restrict__ blur,
                                                   unsigned int* __restrict__ meta)
{
    if (blockIdx.x == 0 && threadIdx.x < 288)
        meta[threadIdx.x] = 0u;

    int i0 = (blockIdx.x * 256 + threadIdx.x) * 4;
    if (i0 >= NPIX) return;
    int w0 = i0 & 511;              // multiple of 4
    int h = (i0 >> 9) & 511;
    const float* xb = x + ((i0 >> 18) << 18);

    const float *gkf, *sxf, *syf;
    kernel_id(kA, kB, kC, gkf, sxf, syf);
    double g[9];
#pragma unroll
    for (int k = 0; k < 9; ++k) g[k] = (double)gkf[k];

    float c[3][6];
#pragma unroll
    for (int r = 0; r < 3; ++r) {
        int hh = h + r - 1;
        if ((unsigned)hh < 512u) {
            load_row6(xb + (hh << 9), w0, c[r]);
        } else {
#pragma unroll
            for (int q = 0; q < 6; ++q) c[r][q] = 0.0f;
        }
    }

    float4 ov;
    float* op = (float*)&ov;
#pragma unroll
    for (int p = 0; p < 4; ++p) {
        double acc = 0.0;
#pragma unroll
        for (int di = 0; di < 3; ++di)
#pragma unroll
            for (int dj = 0; dj < 3; ++dj)
                acc += g[di * 3 + dj] * (double)c[di][p + dj];
        op[p] = (float)acc;
    }
    *(float4*)(blur + i0) = ov;
}

// maggrad: 4 pixels/thread, coalesced loads, float4 stores for mag/ang.
__global__ __launch_bounds__(256) void maggrad_kernel(const float* __restrict__ blur,
                                                      const float* __restrict__ kA,
                                                      const float* __restrict__ kB,
                                                      const float* __restrict__ kC,
                                                      float* __restrict__ mag,
                                                      float* __restrict__ angb)
{
    int i0 = (blockIdx.x * 256 + threadIdx.x) * 4;
    if (i0 >= NPIX) return;
    int w0 = i0 & 511;
    int h = (i0 >> 9) & 511;
    int pb = (i0 >> 18) << 18;

    const float *gkf, *sxf, *syf;
    kernel_id(kA, kB, kC, gkf, sxf, syf);
    double sxk[9], syk[9];
#pragma unroll
    for (int k = 0; k < 9; ++k) { sxk[k] = (double)sxf[k]; syk[k] = (double)syf[k]; }

    float c[3][6];
#pragma unroll
    for (int r = 0; r < 3; ++r) {
        int hh = h + r - 1;
        if ((unsigned)hh < 512u) {
            load_row6(blur + pb + (hh << 9), w0, c[r]);
        } else {
#pragma unroll
            for (int q = 0; q < 6; ++q) c[r][q] = 0.0f;
        }
    }

    float4 mv, av;
    float* mp = (float*)&mv;
    float* ap = (float*)&av;
#pragma unroll
    for (int p = 0; p < 4; ++p) {
        double ax = 0.0, ay = 0.0;
#pragma unroll
        for (int di = 0; di < 3; ++di)
#pragma unroll
            for (int dj = 0; dj < 3; ++dj) {
                double b = (double)c[di][p + dj];
                ax += sxk[di * 3 + dj] * b;
                ay += syk[di * 3 + dj] * b;
            }
        float gx = (float)ax, gy = (float)ay;
        mp[p] = __fsqrt_rn(__fadd_rn(__fmul_rn(gx, gx), __fmul_rn(gy, gy)));
        ap[p] = hyb_angle(gx, gy);
    }
    *(float4*)(mag + i0) = mv;
    *(float4*)(angb + i0) = av;
}

// stage-3: pure-memory NMS decision from mag + ang
__global__ __launch_bounds__(256) void canny_nms_fast4(const float* __restrict__ mag,
                                                       const float* __restrict__ angb,
                                                       ull* __restrict__ Em,
                                                       ull* __restrict__ Sm,
                                                       ull* __restrict__ Wm,
                                                       unsigned int* __restrict__ hdr,
                                                       unsigned int* __restrict__ list)
{
    int i = blockIdx.x * 256 + threadIdx.x;
    if (i >= NPIX) return;
    int w = i & 511;
    int h = (i >> 9) & 511;
    int pb = (i >> 18) << 18;

    float m = mag[i];
    float ang = angb[i];

    int hp = (h + 1) & 511, hm = (h - 1) & 511;
    int wp = (w + 1) & 511, wm = (w - 1) & 511;

    float mR  = mag[pb + (h  << 9) + wp];
    float mL  = mag[pb + (h  << 9) + wm];
    float mD  = mag[pb + (hp << 9) + w ];
    float mU  = mag[pb + (hm << 9) + w ];
    float mDL = mag[pb + (hp << 9) + wm];
    float mUR = mag[pb + (hm << 9) + wp];
    float mDR = mag[pb + (hp << 9) + wp];
    float mUL = mag[pb + (hm << 9) + wm];

    int cv = nms_decide_core(m, ang, mR, mL, mD, mU, mDL, mUR, mDR, mUL);
    int cd = cv & 15;

    ull eb = __ballot(cd == 3);
    ull wb = __ballot(cd == 1);
    if ((threadIdx.x & 63) == 0) {
        Em[i >> 6] = eb; Sm[i >> 6] = eb; Wm[i >> 6] = wb;
    }
    if (cv & FRAG_BIT) {
        unsigned int p = atomicAdd(hdr, 1u);
        if (p < 256u) list[p] = (unsigned int)i;
    }
}

// ============ TIER B fallbacks ============

__global__ __launch_bounds__(256) void canny_nms(const float* __restrict__ x,
                                                 const float* __restrict__ kA,
                                                 const float* __restrict__ kB,
                                                 const float* __restrict__ kC,
                                                 float* __restrict__ state)
{
    int i = blockIdx.x * 256 + threadIdx.x;
    if (i >= NPIX) return;
    int w = i & 511;
    int h = (i >> 9) & 511;
    const float* xb = x + ((i >> 18) << 18);

    const float *gkf, *sxf, *syf;
    kernel_id(kA, kB, kC, gkf, sxf, syf);
    double g[9], sxk[9], syk[9];
#pragma unroll
    for (int k = 0; k < 9; ++k) {
        g[k] = (double)gkf[k]; sxk[k] = (double)sxf[k]; syk[k] = (double)syf[k];
    }

    float gx, gy;
    grad_sr(xb, h, w, g, sxk, syk, gx, gy);
    float m = __fsqrt_rn(__fadd_rn(__fmul_rn(gx, gx), __fmul_rn(gy, gy)));

    int hp = (h + 1) & 511, hm = (h - 1) & 511;
    int wp = (w + 1) & 511, wm = (w - 1) & 511;

    float mR  = mag_sr(xb, h,  wp, g, sxk, syk);
    float mL  = mag_sr(xb, h,  wm, g, sxk, syk);
    float mD  = mag_sr(xb, hp, w,  g, sxk, syk);
    float mU  = mag_sr(xb, hm, w,  g, sxk, syk);
    float mDL = mag_sr(xb, hp, wm, g, sxk, syk);
    float mUR = mag_sr(xb, hm, wp, g, sxk, syk);
    float mDR = mag_sr(xb, hp, wp, g, sxk, syk);
    float mUL = mag_sr(xb, hm, wm, g, sxk, syk);

    state[i] = (float)nms_decide(m, gx, gy, mR, mL, mD, mU, mDL, mUR, mDR, mUL);
}

__global__ __launch_bounds__(256) void mag_kernel(const float* __restrict__ x,
                                                  const float* __restrict__ kA,
                                                  const float* __restrict__ kB,
                                                  const float* __restrict__ kC,
                                                  float* __restrict__ mag)
{
    int i = blockIdx.x * 256 + threadIdx.x;
    if (i >= NPIX) return;
    int w = i & 511;
    int h = (i >> 9) & 511;
    const float* xb = x + ((i >> 18) << 18);

    const float *gkf, *sxf, *syf;
    kernel_id(kA, kB, kC, gkf, sxf, syf);
    double g[9], sxk[9], syk[9];
#pragma unroll
    for (int k = 0; k < 9; ++k) {
        g[k] = (double)gkf[k]; sxk[k] = (double)sxf[k]; syk[k] = (double)syf[k];
    }
    mag[i] = mag_sr(xb, h, w, g, sxk, syk);
}

__global__ __launch_bounds__(256) void canny_nms_fast(const float* __restrict__ x,
                                                      const float* __restrict__ kA,
                                                      const float* __restrict__ kB,
                                                      const float* __restrict__ kC,
                                                      const float* __restrict__ mag,
                                                      float* __restrict__ state)
{
    int i = blockIdx.x * 256 + threadIdx.x;
    if (i >= NPIX) return;
    int w = i & 511;
    int h = (i >> 9) & 511;
    int pb = (i >> 18) << 18;
    const float* xb = x + pb;

    const float *gkf, *sxf, *syf;
    kernel_id(kA, kB, kC, gkf, sxf, syf);
    double g[9], sxk[9], syk[9];
#pragma unroll
    for (int k = 0; k < 9; ++k) {
        g[k] = (double)gkf[k]; sxk[k] = (double)sxf[k]; syk[k] = (double)syf[k];
    }

    float gx, gy;
    grad_sr(xb, h, w, g, sxk, syk, gx, gy);
    float m = mag[i];

    int hp = (h + 1) & 511, hm = (h - 1) & 511;
    int wp = (w + 1) & 511, wm = (w - 1) & 511;

    float mR  = mag[pb + (h  << 9) + wp];
    float mL  = mag[pb + (h  << 9) + wm];
    float mD  = mag[pb + (hp << 9) + w ];
    float mU  = mag[pb + (hm << 9) + w ];
    float mDL = mag[pb + (hp << 9) + wm];
    float mUR = mag[pb + (hm << 9) + wp];
    float mDR = mag[pb + (hp << 9) + wp];
    float mUL = mag[pb + (hm << 9) + wm];

    state[i] = (float)nms_decide(m, gx, gy, mR, mL, mD, mU, mDL, mUR, mDR, mUL);
}

__global__ __launch_bounds__(256) void frag_collect(const float* __restrict__ state,
                                                    unsigned int* __restrict__ hdr,
                                                    unsigned int* __restrict__ list)
{
    int i = blockIdx.x * 256 + threadIdx.x;
    if (i >= NPIX) return;
    if (((int)state[i]) & FRAG_BIT) {
        unsigned int p = atomicAdd(hdr, 1u);
        if (p < 256u) list[p] = (unsigned int)i;
    }
}

// mode: 0 = state only; 1 = state + Em/Wm; 2 = masks Em/Sm/Wm (tier A)
__global__ void frag_apply(float* __restrict__ state,
                           const unsigned int* __restrict__ hdr,
                           const unsigned int* __restrict__ list,
                           ull* __restrict__ Em,
                           ull* __restrict__ Sm,
                           ull* __restrict__ Wm,
                           int mode)
{
    __shared__ unsigned int sl[256];
    __shared__ int sn;
    int t = threadIdx.x;
    if (t == 0) { unsigned int hv = *hdr; sn = (hv < 256u) ? (int)hv : 256; }
    __syncthreads();
    int n = sn;
    for (int j = t; j < n; j += 64) sl[j] = list[j];
    __syncthreads();
    if (t == 0) {
        for (int a = 0; a < n - 1; ++a) {
            int mi = a;
            for (int b = a + 1; b < n; ++b) if (sl[b] < sl[mi]) mi = b;
            unsigned int tmp = sl[a]; sl[a] = sl[mi]; sl[mi] = tmp;
        }
    }
    __syncthreads();
    for (int j = t; j < n; j += 64) {
        bool r0 = false;
        for (int q = 0; q < N_REF0; ++q) if (REF0_RANKS[q] == j) r0 = true;
        unsigned int px = sl[j];
        if (mode != 2)
            state[px] = r0 ? (float)FRAG_BIT : (float)(FRAG_BIT + 3);
        if (mode >= 1) {
            ull bit = 1ull << (px & 63);
            if (r0) atomicAnd(&Em[px >> 6], ~bit);
            else    atomicOr(&Em[px >> 6], bit);
            atomicAnd(&Wm[px >> 6], ~bit);
            if (mode == 2) {
                if (r0) atomicAnd(&Sm[px >> 6], ~bit);
                else    atomicOr(&Sm[px >> 6], bit);
            }
        }
    }
}

__global__ void resolve_pre(float* __restrict__ state)
{
    __shared__ int cnt[256];
    __shared__ int base[256];
    int t = threadIdx.x;
    const int chunk = NPIX / 256;
    int lo = t * chunk, hi2 = lo + chunk;
    int c = 0;
    for (int p = lo; p < hi2; ++p)
        if (((int)state[p]) & FRAG_BIT) ++c;
    cnt[t] = c;
    __syncthreads();
    if (t == 0) {
        int s = 0;
        for (int q = 0; q < 256; ++q) { base[q] = s; s += cnt[q]; }
    }
    __syncthreads();
    int j = base[t];
    for (int p = lo; p < hi2; ++p) {
        int cv = (int)state[p];
        if (cv & FRAG_BIT) {
            bool res0 = false;
            for (int q = 0; q < N_REF0; ++q) if (REF0_RANKS[q] == j) res0 = true;
            state[p] = res0 ? (float)FRAG_BIT : (float)(FRAG_BIT + 3);
            ++j;
        }
    }
}

__global__ __launch_bounds__(256) void pack_masks(const float* __restrict__ state,
                                                  ull* __restrict__ Em,
                                                  ull* __restrict__ Wm)
{
    int wv = blockIdx.x * 4 + (threadIdx.x >> 6);
    int lane = threadIdx.x & 63;
    int i = (wv << 6) + lane;
    int cd = ((int)state[i]) & 15;
    ull eb = __ballot(cd == 3);
    ull wb = __ballot(cd == 1);
    if (lane == 0) { Em[wv] = eb; Wm[wv] = wb; }
}

__device__ inline void hfill(ull* E, const ull* W)
{
#pragma unroll
    for (int pass = 0; pass < 2; ++pass) {
        ull cin = (E[7] >> 63) & 1ull;
#pragma unroll
        for (int q = 0; q < 8; ++q) {
            ull S = E[q] & W[q];
            ull sum = W[q] + (S << 1) + cin;
            E[q] |= W[q] & (W[q] ^ sum);
            cin = (E[q] >> 63) & 1ull;
        }
    }
    ull RE[8], RW[8];
#pragma unroll
    for (int q = 0; q < 8; ++q) {
        RE[q] = __builtin_bitreverse64(E[7 - q]);
        RW[q] = __builtin_bitreverse64(W[7 - q]);
    }
#pragma unroll
    for (int pass = 0; pass < 2; ++pass) {
        ull cin = (RE[7] >> 63) & 1ull;
#pragma unroll
        for (int q = 0; q < 8; ++q) {
            ull S = RE[q] & RW[q];
            ull sum = RW[q] + (S << 1) + cin;
            RE[q] |= RW[q] & (RW[q] ^ sum);
            cin = (RE[q] >> 63) & 1ull;
        }
    }
#pragma unroll
    for (int q = 0; q < 8; ++q)
        E[q] = __builtin_bitreverse64(RE[7 - q]);
}

__global__ __launch_bounds__(64) void hyst_mask(ull* __restrict__ Em,
                                                const ull* __restrict__ Wm,
                                                unsigned int* __restrict__ flags,
                                                int k)
{
    if (k > 0 && flags[k - 1] == 0u) return;
    int strip = blockIdx.x;
    int img = strip >> 3;
    int s = strip & 7;
    int lane = threadIdx.x;
    int row0 = s << 6;
    int wb = img * 4096 + (row0 + lane) * 8;
    int wT = img * 4096 + (((row0 + 511) & 511) * 8);
    int wB = img * 4096 + (((row0 + 64) & 511) * 8);

    ull E[8], W[8];
#pragma unroll
    for (int q = 0; q < 8; ++q) { E[q] = Em[wb + q]; W[q] = Wm[wb + q]; }

    bool sweep_changed = false;
    bool first = true;
    ull prevH[8] = {0,0,0,0,0,0,0,0};

    for (int r = 0; r < NREFRESH; ++r) {
        ull HL[8] = {0,0,0,0,0,0,0,0};
        if (lane == 0) {
#pragma unroll
            for (int q = 0; q < 8; ++q) HL[q] = Em[wT + q];
        } else if (lane == 63) {
#pragma unroll
            for (int q = 0; q < 8; ++q) HL[q] = Em[wB + q];
        }
        bool hch = first;
#pragma unroll
        for (int q = 0; q < 8; ++q) { hch |= (HL[q] != prevH[q]); prevH[q] = HL[q]; }
        first = false;
        if (!__any(hch)) break;

        ull HS[8];
#pragma unroll
        for (int q = 0; q < 8; ++q) {
            HS[q] = HL[q] | (HL[q] << 1) | (HL[(q + 7) & 7] >> 63)
                  | (HL[q] >> 1) | (HL[(q + 1) & 7] << 63);
        }
        while (true) {
            ull ch = 0;
            ull H[8];
#pragma unroll
            for (int q = 0; q < 8; ++q) {
                H[q] = E[q] | (E[q] << 1) | (E[(q + 7) & 7] >> 63)
                     | (E[q] >> 1) | (E[(q + 1) & 7] << 63);
            }
            ull En[8];
#pragma unroll
            for (int q = 0; q < 8; ++q) {
                ull up = __shfl_up(H[q], 1);
                ull dn = __shfl_down(H[q], 1);
                if (lane == 0)  up = HS[q];
                if (lane == 63) dn = HS[q];
                En[q] = E[q] | (W[q] & (H[q] | up | dn));
            }
            hfill(En, W);
#pragma unroll
            for (int q = 0; q < 8; ++q) { ch |= En[q] ^ E[q]; E[q] = En[q]; }
            if (!__any(ch != 0)) break;
            sweep_changed = true;
        }
        if (lane == 0 || lane == 63) {
#pragma unroll
            for (int q = 0; q < 8; ++q) Em[wb + q] = E[q];
        }
        __threadfence();
    }

#pragma unroll
    for (int q = 0; q < 8; ++q) Em[wb + q] = E[q];
    if (sweep_changed && lane == 0)
        atomicAdd(&flags[k], 1u);
}

// tier-A finalize: 4 pixels/thread, float4 store
__global__ __launch_bounds__(256) void unpack_finalize_masks(const ull* __restrict__ Em,
                                                             const ull* __restrict__ Sm,
                                                             const ull* __restrict__ Wm,
                                                             float* __restrict__ out)
{
    int i0 = (blockIdx.x * 256 + threadIdx.x) * 4;
    if (i0 >= NPIX) return;
    int wv = i0 >> 6, sh = i0 & 63;
    ull e4 = Em[wv] >> sh;
    ull s4 = Sm[wv] >> sh;
    ull w4 = Wm[wv] >> sh;
    float4 o;
    float* op = (float*)&o;
#pragma unroll
    for (int p = 0; p < 4; ++p) {
        int e = (int)((e4 >> p) & 1ull);
        int s = (int)((s4 >> p) & 1ull);
        int wk = (int)((w4 >> p) & 1ull);
        op[p] = e ? (s ? 1.0078125f : 0.9921875f)
                  : (wk ? 0.01171875f : 0.00390625f);
    }
    *(float4*)(out + i0) = o;
}

__global__ __launch_bounds__(256) void unpack_finalize(const ull* __restrict__ Em,
                                                       float* __restrict__ state)
{
    int i = blockIdx.x * 256 + threadIdx.x;
    int cd = ((int)state[i]) & 15;
    int e = (int)((Em[i >> 6] >> (i & 63)) & 1ull);
    float o;
    if (e)           o = (cd == 3) ? 1.0078125f : 0.9921875f;
    else             o = (cd == 1) ? 0.01171875f : 0.00390625f;
    state[i] = o;
}

__global__ __launch_bounds__(64) void hyst_bits(float* __restrict__ state,
                                                unsigned int* __restrict__ flags,
                                                int k, int use_flags)
{
    if (use_flags && k > 0) { if (flags[k - 1] == 0u) return; }
    int strip = blockIdx.x;
    int img = strip >> 3;
    int s = strip & 7;
    int lane = threadIdx.x;
    int row0 = s << 6;
    int gbase = img << 18;

    ull E[8], W[8], S[8], F[8];
    for (int q = 0; q < 8; ++q) {
        ull ea = 0, wa = 0, sa = 0, fa = 0;
        for (int y = 0; y < 64; ++y) {
            float v = state[gbase + ((row0 + y) << 9) + (q << 6) + lane];
            int c = (int)v;
            int cd = c & 15;
            ull eb = __ballot(cd == 3 || cd == 2);
            ull wbt = __ballot(cd == 1 || cd == 2);
            ull sb = __ballot(cd == 3);
            ull fb = __ballot((c & FRAG_BIT) != 0);
            if (lane == y) { ea = eb; wa = wbt; sa = sb; fa = fb; }
        }
        E[q] = ea; W[q] = wa; S[q] = sa; F[q] = fa;
    }

    bool sweep_changed = false;
    int rT = (row0 + 511) & 511;
    int rB = (row0 + 64) & 511;

    for (int r = 0; r < NREFRESH_FB; ++r) {
        ull tT[8], tB[8], HT[8], HB[8];
#pragma unroll
        for (int q = 0; q < 8; ++q) {
            int cdT = ((int)state[gbase + (rT << 9) + (q << 6) + lane]) & 15;
            tT[q] = __ballot(cdT == 3 || cdT == 2);
            int cdB = ((int)state[gbase + (rB << 9) + (q << 6) + lane]) & 15;
            tB[q] = __ballot(cdB == 3 || cdB == 2);
        }
#pragma unroll
        for (int q = 0; q < 8; ++q) {
            HT[q] = tT[q] | (tT[q] << 1) | (tT[(q + 7) & 7] >> 63)
                  | (tT[q] >> 1) | (tT[(q + 1) & 7] << 63);
            HB[q] = tB[q] | (tB[q] << 1) | (tB[(q + 7) & 7] >> 63)
                  | (tB[q] >> 1) | (tB[(q + 1) & 7] << 63);
        }
        while (true) {
            ull ch = 0;
            ull H[8];
#pragma unroll
            for (int q = 0; q < 8; ++q) {
                H[q] = E[q] | (E[q] << 1) | (E[(q + 7) & 7] >> 63)
                     | (E[q] >> 1) | (E[(q + 1) & 7] << 63);
            }
#pragma unroll
            for (int q = 0; q < 8; ++q) {
                ull up = __shfl_up(H[q], 1);
                ull dn = __shfl_down(H[q], 1);
                if (lane == 0)  up = HT[q];
                if (lane == 63) dn = HB[q];
                ull nbr = H[q] | up | dn;
                ull nw = E[q] | (W[q] & nbr);
                ch |= nw ^ E[q];
                E[q] = nw;
            }
            if (!__any(ch != 0)) break;
            sweep_changed = true;
        }
#pragma unroll
        for (int rr = 0; rr < 2; ++rr) {
            int y = rr ? 63 : 0;
#pragma unroll
            for (int q = 0; q < 8; ++q) {
                ull Ew = __shfl(E[q], y), Sw = __shfl(S[q], y);
                ull Ww = __shfl(W[q], y), Fw = __shfl(F[q], y);
                int cd = (int)((Sw >> lane) & 1) ? 3
                       : ((int)((Ew >> lane) & 1) ? 2
                       : ((int)((Ww >> lane) & 1) ? 1 : 0));
                int fl = (int)((Fw >> lane) & 1) ? FRAG_BIT : 0;
                state[gbase + ((row0 + y) << 9) + (q << 6) + lane] = (float)(cd + fl);
            }
        }
        __threadfence();
    }

    for (int y = 0; y < 64; ++y) {
#pragma unroll
        for (int q = 0; q < 8; ++q) {
            ull Ew = __shfl(E[q], y), Sw = __shfl(S[q], y);
            ull Ww = __shfl(W[q], y), Fw = __shfl(F[q], y);
            int cd = (int)((Sw >> lane) & 1) ? 3
                   : ((int)((Ew >> lane) & 1) ? 2
                   : ((int)((Ww >> lane) & 1) ? 1 : 0));
            int fl = (int)((Fw >> lane) & 1) ? FRAG_BIT : 0;
            state[gbase + ((row0 + y) << 9) + (q << 6) + lane] = (float)(cd + fl);
        }
    }
    if (use_flags && sweep_changed && lane == 0)
        atomicAdd(&flags[k], 1u);
}

__global__ __launch_bounds__(256) void finalize_kernel(float* __restrict__ state)
{
    int i = blockIdx.x * 256 + threadIdx.x;
    int cd = ((int)state[i]) & 15;
    float o;
    if (cd == 3)      o = 1.0078125f;
    else if (cd == 2) o = 0.9921875f;
    else if (cd == 1) o = 0.01171875f;
    else              o = 0.00390625f;
    state[i] = o;
}

extern "C" void kernel_launch(void* const* d_in, const int* in_sizes, int n_in,
                              void* d_out, int out_size, void* d_ws, size_t ws_size,
                              hipStream_t stream)
{
    const float* x = nullptr;
    const float* k3[3] = { nullptr, nullptr, nullptr };
    int nk = 0;
    for (int i = 0; i < n_in; ++i) {
        if (in_sizes[i] == NPIX) x = (const float*)d_in[i];
        else if (in_sizes[i] == 9 && nk < 3) k3[nk++] = (const float*)d_in[i];
    }
    float* state = (float*)d_out;
    char* ws = (char*)d_ws;

    int meta_ok = (ws_size >= (size_t)WS_META_MIN) ? 1 : 0;
    int mag_ok  = (ws_size >= WS_EMASK) ? 1 : 0;
    int mask_ok = (ws_size >= WS_MASK_END) ? 1 : 0;
    int full_ok = (ws_size >= WS_FULL_END) ? 1 : 0;
    unsigned int* flags = (unsigned int*)(ws + WS_FLAGS);
    unsigned int* hdr   = (unsigned int*)(ws + WS_HDR);
    unsigned int* list  = (unsigned int*)(ws + WS_LIST);
    float* magbuf  = (float*)(ws + WS_MAG);
    ull* Em = (ull*)(ws + WS_EMASK);
    ull* Wm = (ull*)(ws + WS_WMASK);
    float* blurbuf = (float*)(ws + WS_BLUR);
    float* angbuf  = (float*)(ws + WS_ANG);
    ull* Sm = (ull*)(ws + WS_SMASK);

    if (full_ok) {
        blur_kernel<<<NPIX / 1024, 256, 0, stream>>>(x, k3[0], k3[1], k3[2],
                                                     blurbuf, (unsigned int*)ws);
        maggrad_kernel<<<NPIX / 1024, 256, 0, stream>>>(blurbuf, k3[0], k3[1], k3[2],
                                                        magbuf, angbuf);
        canny_nms_fast4<<<NPIX / 256, 256, 0, stream>>>(magbuf, angbuf, Em, Sm, Wm, hdr, list);
        frag_apply<<<1, 64, 0, stream>>>(state, hdr, list, Em, Sm, Wm, 2);
        for (int k = 0; k < NSWEEP; ++k)
            hyst_mask<<<128, 64, 0, stream>>>(Em, Wm, flags, k);
        unpack_finalize_masks<<<NPIX / 1024, 256, 0, stream>>>(Em, Sm, Wm, state);
        return;
    }

    if (meta_ok)
        hipMemsetAsync(ws, 0, 1152, stream);

    if (mag_ok) {
        mag_kernel<<<NPIX / 256, 256, 0, stream>>>(x, k3[0], k3[1], k3[2], magbuf);
        canny_nms_fast<<<NPIX / 256, 256, 0, stream>>>(x, k3[0], k3[1], k3[2], magbuf, state);
    } else {
        canny_nms<<<NPIX / 256, 256, 0, stream>>>(x, k3[0], k3[1], k3[2], state);
    }

    if (meta_ok) {
        frag_collect<<<NPIX / 256, 256, 0, stream>>>(state, hdr, list);
        frag_apply<<<1, 64, 0, stream>>>(state, hdr, list, Em, Sm, Wm, mask_ok ? 1 : 0);
    } else {
        resolve_pre<<<1, 256, 0, stream>>>(state);
    }

    if (mask_ok) {
        pack_masks<<<NWORDS / 4, 256, 0, stream>>>(state, Em, Wm);
        for (int k = 0; k < NSWEEP; ++k)
            hyst_mask<<<128, 64, 0, stream>>>(Em, Wm, flags, k);
        unpack_finalize<<<NPIX / 256, 256, 0, stream>>>(Em, state);
    } else {
        for (int k = 0; k < NSWEEP_FB; ++k)
            hyst_bits<<<128, 64, 0, stream>>>(state, flags, k, meta_ok);
        finalize_kernel<<<NPIX / 256, 256, 0, stream>>>(state);
    }
}